// Round 1
// baseline (1173.761 us; speedup 1.0000x reference)
//
#include <hip/hip_runtime.h>
#include <hip/hip_bf16.h>

#define INV1P 0.9999950000374997f

// ---------------- graph-structure kernels ----------------

__global__ __launch_bounds__(256) void k_init_deg(int* __restrict__ deg, int n) {
    int i = blockIdx.x * 256 + threadIdx.x;
    if (i < n) deg[i] = 1;  // self-loop
}

__global__ __launch_bounds__(256) void k_count(const int* __restrict__ dst, int* __restrict__ deg, int e) {
    int i = blockIdx.x * 256 + threadIdx.x;
    if (i < e) atomicAdd(&deg[dst[i]], 1);
}

__global__ __launch_bounds__(256) void k_dinv(const int* __restrict__ deg, float* __restrict__ dinv, int n) {
    int i = blockIdx.x * 256 + threadIdx.x;
    if (i < n) dinv[i] = rsqrtf((float)deg[i]);
}

// exclusive scan of (deg[i]-1) -> rowptr, in 3 stages. items/block = 1024.
__global__ __launch_bounds__(256) void k_scan1(const int* __restrict__ deg, int* __restrict__ part,
                                               int* __restrict__ bsums, int n) {
    __shared__ int sh[256];
    int tid = threadIdx.x;
    int base = blockIdx.x * 1024 + tid * 4;
    int v[4]; int s = 0;
    #pragma unroll
    for (int j = 0; j < 4; j++) {
        v[j] = (base + j < n) ? (deg[base + j] - 1) : 0;
        s += v[j];
    }
    sh[tid] = s; __syncthreads();
    for (int off = 1; off < 256; off <<= 1) {
        int t2 = (tid >= off) ? sh[tid - off] : 0;
        __syncthreads();
        sh[tid] += t2;
        __syncthreads();
    }
    int incl = sh[tid];
    int run = incl - s;  // exclusive for this thread's first item
    #pragma unroll
    for (int j = 0; j < 4; j++) {
        if (base + j < n) part[base + j] = run;
        run += v[j];
    }
    if (tid == 255) bsums[blockIdx.x] = incl;
}

__global__ __launch_bounds__(128) void k_scan2(int* __restrict__ bsums, int nb) {
    __shared__ int sh[128];
    int tid = threadIdx.x;
    int v = (tid < nb) ? bsums[tid] : 0;
    sh[tid] = v; __syncthreads();
    for (int off = 1; off < 128; off <<= 1) {
        int t2 = (tid >= off) ? sh[tid - off] : 0;
        __syncthreads();
        sh[tid] += t2;
        __syncthreads();
    }
    if (tid < nb) bsums[tid] = sh[tid] - v;  // exclusive
}

__global__ __launch_bounds__(256) void k_scan3(int* __restrict__ rowptr, const int* __restrict__ bsums,
                                               int* __restrict__ cursor, int n, int totalE) {
    int i = blockIdx.x * 256 + threadIdx.x;
    if (i < n) {
        int vv = rowptr[i] + bsums[i >> 10];
        rowptr[i] = vv;
        cursor[i] = vv;
    }
    if (i == 0) rowptr[n] = totalE;
}

__global__ __launch_bounds__(256) void k_fill(const int* __restrict__ src, const int* __restrict__ dst,
                                              const float* __restrict__ dinv, int* __restrict__ cursor,
                                              int* __restrict__ csr_src, float* __restrict__ csr_norm, int e) {
    int i = blockIdx.x * 256 + threadIdx.x;
    if (i < e) {
        int s = src[i], d = dst[i];
        int slot = atomicAdd(&cursor[d], 1);
        csr_src[slot] = s;
        csr_norm[slot] = dinv[s] * dinv[d];
    }
}

// ---------------- dense kernels ----------------

// Y[n,128] = X[n,128] @ W[128,128], fp32. 8 rows/block, 256 threads.
__global__ __launch_bounds__(256) void k_gemm128(const float* __restrict__ X, const float* __restrict__ W,
                                                 float* __restrict__ Y, int nrows) {
    __shared__ float xs[8][128];
    int tid = threadIdx.x;
    int rowbase = blockIdx.x * 8;
    {
        int r = tid >> 5;          // 0..7
        int c4 = tid & 31;         // float4 col
        int grow = rowbase + r;
        float4 v = make_float4(0.f, 0.f, 0.f, 0.f);
        if (grow < nrows) v = ((const float4*)X)[(size_t)grow * 32 + c4];
        ((float4*)&xs[r][0])[c4] = v;
    }
    __syncthreads();
    int cq = tid & 31;   // col quad: cols cq*4 .. cq*4+3
    int r  = tid >> 5;   // row within tile
    float4 acc = make_float4(0.f, 0.f, 0.f, 0.f);
    #pragma unroll 8
    for (int k = 0; k < 128; k++) {
        float xv = xs[r][k];
        float4 w = ((const float4*)W)[k * 32 + cq];
        acc.x += xv * w.x; acc.y += xv * w.y; acc.z += xv * w.z; acc.w += xv * w.w;
    }
    int grow = rowbase + r;
    if (grow < nrows) ((float4*)Y)[(size_t)grow * 32 + cq] = acc;
}

// out[node] = relu(bn(segsum + bias)); 2 nodes per 256-thread block.
__global__ __launch_bounds__(256) void k_aggregate(const float* __restrict__ Hpre, const int* __restrict__ rowptr,
                                                   const int* __restrict__ csr_src, const float* __restrict__ csr_norm,
                                                   const float* __restrict__ dinv,
                                                   const float* __restrict__ bias, const float* __restrict__ gamma,
                                                   const float* __restrict__ beta,
                                                   float* __restrict__ out, int nnodes) {
    int node = blockIdx.x * 2 + (threadIdx.x >> 7);
    int t = threadIdx.x & 127;
    if (node >= nnodes) return;
    float di = dinv[node];
    float acc = Hpre[(size_t)node * 128 + t] * (di * di);   // self-loop
    int s = rowptr[node], e = rowptr[node + 1];
    int j = s;
    for (; j + 3 < e; j += 4) {
        int u0 = csr_src[j], u1 = csr_src[j + 1], u2 = csr_src[j + 2], u3 = csr_src[j + 3];
        float n0 = csr_norm[j], n1 = csr_norm[j + 1], n2 = csr_norm[j + 2], n3 = csr_norm[j + 3];
        acc += Hpre[(size_t)u0 * 128 + t] * n0;
        acc += Hpre[(size_t)u1 * 128 + t] * n1;
        acc += Hpre[(size_t)u2 * 128 + t] * n2;
        acc += Hpre[(size_t)u3 * 128 + t] * n3;
    }
    for (; j < e; j++) {
        int u = csr_src[j];
        acc += Hpre[(size_t)u * 128 + t] * csr_norm[j];
    }
    float v = acc + bias[t];
    v = fmaf(gamma[t] * INV1P, v, beta[t]);
    out[(size_t)node * 128 + t] = fmaxf(v, 0.f);
}

// pooled sums: 64 consecutive nodes per 128-thread block; batch sorted.
__global__ __launch_bounds__(128) void k_pool(const float* __restrict__ Hf, const int* __restrict__ batch,
                                              float* __restrict__ pooled, float* __restrict__ cnt, int nnodes) {
    int t = threadIdx.x;
    int base = blockIdx.x * 64;
    if (base >= nnodes) return;
    int end = min(base + 64, nnodes);
    float acc = 0.f; int run = 0;
    int cur = batch[base];
    for (int i = base; i < end; i++) {
        int bg = batch[i];
        if (bg != cur) {
            atomicAdd(&pooled[(size_t)cur * 128 + t], acc);
            if (t == 0) atomicAdd(&cnt[cur], (float)run);
            acc = 0.f; run = 0; cur = bg;
        }
        acc += Hf[(size_t)i * 128 + t];
        run++;
    }
    atomicAdd(&pooled[(size_t)cur * 128 + t], acc);
    if (t == 0) atomicAdd(&cnt[cur], (float)run);
}

// classifier: one 64-thread block per graph. 128 -> 64 (relu) -> 10
__global__ __launch_bounds__(64) void k_classifier(const float* __restrict__ pooled, const float* __restrict__ cnt,
                                                   const float* __restrict__ Wc1, const float* __restrict__ bc1,
                                                   const float* __restrict__ Wc2, const float* __restrict__ bc2,
                                                   float* __restrict__ outp, int ngraphs) {
    __shared__ float p[128];
    __shared__ float z[64];
    int g = blockIdx.x;
    int tid = threadIdx.x;
    float inv = 1.0f / fmaxf(cnt[g], 1.0f);
    p[tid]      = pooled[(size_t)g * 128 + tid] * inv;
    p[tid + 64] = pooled[(size_t)g * 128 + 64 + tid] * inv;
    __syncthreads();
    float a = bc1[tid];
    #pragma unroll 8
    for (int k = 0; k < 128; k++) a += p[k] * Wc1[k * 64 + tid];
    z[tid] = fmaxf(a, 0.f);
    __syncthreads();
    if (tid < 10) {
        float o = bc2[tid];
        #pragma unroll 8
        for (int j = 0; j < 64; j++) o += z[j] * Wc2[j * 10 + tid];
        outp[(size_t)g * 10 + tid] = o;
    }
}

// ---------------- launch ----------------

extern "C" void kernel_launch(void* const* d_in, const int* in_sizes, int n_in,
                              void* d_out, int out_size, void* d_ws, size_t ws_size,
                              hipStream_t stream) {
    const float* x      = (const float*)d_in[0];
    const int*   ei     = (const int*)d_in[1];
    const int*   batch  = (const int*)d_in[2];
    const float* W1 = (const float*)d_in[3];  const float* b1 = (const float*)d_in[4];
    const float* W2 = (const float*)d_in[5];  const float* b2 = (const float*)d_in[6];
    const float* W3 = (const float*)d_in[7];  const float* b3 = (const float*)d_in[8];
    const float* g1 = (const float*)d_in[9];  const float* be1 = (const float*)d_in[10];
    const float* g2 = (const float*)d_in[11]; const float* be2 = (const float*)d_in[12];
    const float* g3 = (const float*)d_in[13]; const float* be3 = (const float*)d_in[14];
    const float* Wc1 = (const float*)d_in[15]; const float* bc1 = (const float*)d_in[16];
    const float* Wc2 = (const float*)d_in[17]; const float* bc2 = (const float*)d_in[18];

    const int N = in_sizes[0] / 128;
    const int E = in_sizes[1] / 2;
    const int G = out_size / 10;
    const int* srcp = ei;
    const int* dstp = ei + E;

    // workspace layout
    char* ws = (char*)d_ws;
    size_t off = 0;
    float* bufA = (float*)(ws + off);  off += (size_t)N * 128 * 4;
    float* bufB = (float*)(ws + off);  off += (size_t)N * 128 * 4;
    int*   csr_src  = (int*)(ws + off);   off += (size_t)E * 4;
    float* csr_norm = (float*)(ws + off); off += (size_t)E * 4;
    int*   deg    = (int*)(ws + off);   off += (size_t)N * 4;
    float* dinv   = (float*)(ws + off); off += (size_t)N * 4;
    int*   rowptr = (int*)(ws + off);   off += (size_t)(N + 1) * 4;
    int*   cursor = (int*)(ws + off);   off += (size_t)N * 4;
    float* pooled = (float*)(ws + off); off += (size_t)G * 128 * 4;
    float* cnt    = (float*)(ws + off); off += (size_t)G * 4;
    int*   bsums  = (int*)(ws + off);   off += 256 * 4;
    (void)ws_size;

    int gN  = (N + 255) / 256;
    int gE  = (E + 255) / 256;
    int nb  = (N + 1023) / 1024;

    // graph structure
    k_init_deg<<<gN, 256, 0, stream>>>(deg, N);
    k_count<<<gE, 256, 0, stream>>>(dstp, deg, E);
    k_dinv<<<gN, 256, 0, stream>>>(deg, dinv, N);
    k_scan1<<<nb, 256, 0, stream>>>(deg, rowptr, bsums, N);
    k_scan2<<<1, 128, 0, stream>>>(bsums, nb);
    k_scan3<<<gN, 256, 0, stream>>>(rowptr, bsums, cursor, N, E);
    k_fill<<<gE, 256, 0, stream>>>(srcp, dstp, dinv, cursor, csr_src, csr_norm, E);

    int gGemm = (N + 7) / 8;
    int gAgg  = (N + 1) / 2;

    // layer 1
    k_gemm128<<<gGemm, 256, 0, stream>>>(x, W1, bufA, N);
    k_aggregate<<<gAgg, 256, 0, stream>>>(bufA, rowptr, csr_src, csr_norm, dinv, b1, g1, be1, bufB, N);
    // layer 2
    k_gemm128<<<gGemm, 256, 0, stream>>>(bufB, W2, bufA, N);
    k_aggregate<<<gAgg, 256, 0, stream>>>(bufA, rowptr, csr_src, csr_norm, dinv, b2, g2, be2, bufB, N);
    // layer 3
    k_gemm128<<<gGemm, 256, 0, stream>>>(bufB, W3, bufA, N);
    k_aggregate<<<gAgg, 256, 0, stream>>>(bufA, rowptr, csr_src, csr_norm, dinv, b3, g3, be3, bufB, N);

    // pooling
    hipMemsetAsync(pooled, 0, ((size_t)G * 128 + G) * 4, stream);
    int gPool = (N + 63) / 64;
    k_pool<<<gPool, 128, 0, stream>>>(bufB, batch, pooled, cnt, N);

    // classifier
    k_classifier<<<G, 64, 0, stream>>>(pooled, cnt, Wc1, bc1, Wc2, bc2, (float*)d_out, G);
}

// Round 2
// 738.683 us; speedup vs baseline: 1.5890x; 1.5890x over previous
//
#include <hip/hip_runtime.h>
#include <hip/hip_bf16.h>

#define INV1P 0.9999950000374997f

// ---------------- graph-structure kernels ----------------

__global__ __launch_bounds__(256) void k_init_deg(int* __restrict__ deg, int n) {
    int i = blockIdx.x * 256 + threadIdx.x;
    if (i < n) deg[i] = 1;  // self-loop
}

__global__ __launch_bounds__(256) void k_count(const int* __restrict__ dst, int* __restrict__ deg, int e) {
    int i = blockIdx.x * 256 + threadIdx.x;
    if (i < e) atomicAdd(&deg[dst[i]], 1);
}

__global__ __launch_bounds__(256) void k_dinv(const int* __restrict__ deg, float* __restrict__ dinv, int n) {
    int i = blockIdx.x * 256 + threadIdx.x;
    if (i < n) dinv[i] = rsqrtf((float)deg[i]);
}

// exclusive scan of (deg[i]-1) -> rowptr, in 3 stages. items/block = 1024.
__global__ __launch_bounds__(256) void k_scan1(const int* __restrict__ deg, int* __restrict__ part,
                                               int* __restrict__ bsums, int n) {
    __shared__ int sh[256];
    int tid = threadIdx.x;
    int base = blockIdx.x * 1024 + tid * 4;
    int v[4]; int s = 0;
    #pragma unroll
    for (int j = 0; j < 4; j++) {
        v[j] = (base + j < n) ? (deg[base + j] - 1) : 0;
        s += v[j];
    }
    sh[tid] = s; __syncthreads();
    for (int off = 1; off < 256; off <<= 1) {
        int t2 = (tid >= off) ? sh[tid - off] : 0;
        __syncthreads();
        sh[tid] += t2;
        __syncthreads();
    }
    int incl = sh[tid];
    int run = incl - s;  // exclusive for this thread's first item
    #pragma unroll
    for (int j = 0; j < 4; j++) {
        if (base + j < n) part[base + j] = run;
        run += v[j];
    }
    if (tid == 255) bsums[blockIdx.x] = incl;
}

__global__ __launch_bounds__(128) void k_scan2(int* __restrict__ bsums, int nb) {
    __shared__ int sh[128];
    int tid = threadIdx.x;
    int v = (tid < nb) ? bsums[tid] : 0;
    sh[tid] = v; __syncthreads();
    for (int off = 1; off < 128; off <<= 1) {
        int t2 = (tid >= off) ? sh[tid - off] : 0;
        __syncthreads();
        sh[tid] += t2;
        __syncthreads();
    }
    if (tid < nb) bsums[tid] = sh[tid] - v;  // exclusive
}

__global__ __launch_bounds__(256) void k_scan3(int* __restrict__ rowptr, const int* __restrict__ bsums,
                                               int* __restrict__ cursor, int n, int totalE) {
    int i = blockIdx.x * 256 + threadIdx.x;
    if (i < n) {
        int vv = rowptr[i] + bsums[i >> 10];
        rowptr[i] = vv;
        cursor[i] = vv;
    }
    if (i == 0) rowptr[n] = totalE;
}

__global__ __launch_bounds__(256) void k_fill(const int* __restrict__ src, const int* __restrict__ dst,
                                              const float* __restrict__ dinv, int* __restrict__ cursor,
                                              int2* __restrict__ csr, int e) {
    int i = blockIdx.x * 256 + threadIdx.x;
    if (i < e) {
        int s = src[i], d = dst[i];
        int slot = atomicAdd(&cursor[d], 1);
        csr[slot] = make_int2(s, __float_as_int(dinv[s] * dinv[d]));
    }
}

// ---------------- dense kernels ----------------

// Y[n,128] = X[n,128] @ W[128,128], fp32.
// 64-row x 128-col tile per 256-thread block; each thread: 8 rows x 4 cols.
__global__ __launch_bounds__(256, 4) void k_gemm128(const float* __restrict__ X, const float* __restrict__ W,
                                                    float* __restrict__ Y, int nrows) {
    __shared__ float xs[64][128];
    int tid = threadIdx.x;
    int rowbase = blockIdx.x * 64;
    {
        const float4* X4 = (const float4*)X;
        #pragma unroll
        for (int i = 0; i < 8; i++) {
            int idx = tid + i * 256;          // 0..2047
            int r = idx >> 5, q = idx & 31;
            int gr = rowbase + r;
            float4 v = make_float4(0.f, 0.f, 0.f, 0.f);
            if (gr < nrows) v = X4[(size_t)gr * 32 + q];
            ((float4*)&xs[r][0])[q] = v;
        }
    }
    __syncthreads();
    int cq = tid & 31;    // col quad: cols cq*4..cq*4+3
    int rg = tid >> 5;    // row group: rows rg*8..rg*8+7
    const float4* W4 = (const float4*)W;
    float4 acc[8];
    #pragma unroll
    for (int r = 0; r < 8; r++) acc[r] = make_float4(0.f, 0.f, 0.f, 0.f);
    #pragma unroll 2
    for (int k4 = 0; k4 < 32; k4++) {
        float4 wv0 = W4[(k4 * 4 + 0) * 32 + cq];
        float4 wv1 = W4[(k4 * 4 + 1) * 32 + cq];
        float4 wv2 = W4[(k4 * 4 + 2) * 32 + cq];
        float4 wv3 = W4[(k4 * 4 + 3) * 32 + cq];
        #pragma unroll
        for (int r = 0; r < 8; r++) {
            float4 av = *((const float4*)&xs[rg * 8 + r][k4 * 4]);
            acc[r].x += av.x * wv0.x + av.y * wv1.x + av.z * wv2.x + av.w * wv3.x;
            acc[r].y += av.x * wv0.y + av.y * wv1.y + av.z * wv2.y + av.w * wv3.y;
            acc[r].z += av.x * wv0.z + av.y * wv1.z + av.z * wv2.z + av.w * wv3.z;
            acc[r].w += av.x * wv0.w + av.y * wv1.w + av.z * wv2.w + av.w * wv3.w;
        }
    }
    #pragma unroll
    for (int r = 0; r < 8; r++) {
        int grow = rowbase + rg * 8 + r;
        if (grow < nrows) ((float4*)Y)[(size_t)grow * 32 + cq] = acc[r];
    }
}

// out[node] = relu(bn(segsum + bias)); one node per wave, float2 per lane.
__global__ __launch_bounds__(256) void k_aggregate(const float* __restrict__ Hpre, const int* __restrict__ rowptr,
                                                   const int2* __restrict__ csr,
                                                   const float* __restrict__ dinv,
                                                   const float* __restrict__ bias, const float* __restrict__ gamma,
                                                   const float* __restrict__ beta,
                                                   float* __restrict__ out, int nnodes) {
    int lane = threadIdx.x & 63;
    int node = blockIdx.x * 4 + (threadIdx.x >> 6);
    if (node >= nnodes) return;
    const float2* H2 = (const float2*)Hpre;
    float di = dinv[node];
    float sl = di * di;
    float2 h0 = H2[(size_t)node * 64 + lane];
    float ax = h0.x * sl, ay = h0.y * sl;
    int s = rowptr[node], e = rowptr[node + 1];
    int j = s;
    for (; j + 3 < e; j += 4) {
        int2 e0 = csr[j], e1 = csr[j + 1], e2 = csr[j + 2], e3 = csr[j + 3];
        float2 v0 = H2[(size_t)(unsigned)e0.x * 64 + lane];
        float2 v1 = H2[(size_t)(unsigned)e1.x * 64 + lane];
        float2 v2 = H2[(size_t)(unsigned)e2.x * 64 + lane];
        float2 v3 = H2[(size_t)(unsigned)e3.x * 64 + lane];
        float n0 = __int_as_float(e0.y), n1 = __int_as_float(e1.y);
        float n2 = __int_as_float(e2.y), n3 = __int_as_float(e3.y);
        ax += v0.x * n0 + v1.x * n1 + v2.x * n2 + v3.x * n3;
        ay += v0.y * n0 + v1.y * n1 + v2.y * n2 + v3.y * n3;
    }
    for (; j < e; j++) {
        int2 e0 = csr[j];
        float2 v0 = H2[(size_t)(unsigned)e0.x * 64 + lane];
        float n0 = __int_as_float(e0.y);
        ax += v0.x * n0;
        ay += v0.y * n0;
    }
    float2 bi = ((const float2*)bias)[lane];
    float2 ga = ((const float2*)gamma)[lane];
    float2 be = ((const float2*)beta)[lane];
    float vx = fmaf(ga.x * INV1P, ax + bi.x, be.x);
    float vy = fmaf(ga.y * INV1P, ay + bi.y, be.y);
    float2 res = make_float2(fmaxf(vx, 0.f), fmaxf(vy, 0.f));
    ((float2*)out)[(size_t)node * 64 + lane] = res;
}

// pooled sums: 64 consecutive nodes per 128-thread block; batch sorted.
__global__ __launch_bounds__(128) void k_pool(const float* __restrict__ Hf, const int* __restrict__ batch,
                                              float* __restrict__ pooled, float* __restrict__ cnt, int nnodes) {
    int t = threadIdx.x;
    int base = blockIdx.x * 64;
    if (base >= nnodes) return;
    int end = min(base + 64, nnodes);
    float acc = 0.f; int run = 0;
    int cur = batch[base];
    for (int i = base; i < end; i++) {
        int bg = batch[i];
        if (bg != cur) {
            atomicAdd(&pooled[(size_t)cur * 128 + t], acc);
            if (t == 0) atomicAdd(&cnt[cur], (float)run);
            acc = 0.f; run = 0; cur = bg;
        }
        acc += Hf[(size_t)i * 128 + t];
        run++;
    }
    atomicAdd(&pooled[(size_t)cur * 128 + t], acc);
    if (t == 0) atomicAdd(&cnt[cur], (float)run);
}

// classifier: one 64-thread block per graph. 128 -> 64 (relu) -> 10
__global__ __launch_bounds__(64) void k_classifier(const float* __restrict__ pooled, const float* __restrict__ cnt,
                                                   const float* __restrict__ Wc1, const float* __restrict__ bc1,
                                                   const float* __restrict__ Wc2, const float* __restrict__ bc2,
                                                   float* __restrict__ outp, int ngraphs) {
    __shared__ float p[128];
    __shared__ float z[64];
    int g = blockIdx.x;
    int tid = threadIdx.x;
    float inv = 1.0f / fmaxf(cnt[g], 1.0f);
    p[tid]      = pooled[(size_t)g * 128 + tid] * inv;
    p[tid + 64] = pooled[(size_t)g * 128 + 64 + tid] * inv;
    __syncthreads();
    float a = bc1[tid];
    #pragma unroll 8
    for (int k = 0; k < 128; k++) a += p[k] * Wc1[k * 64 + tid];
    z[tid] = fmaxf(a, 0.f);
    __syncthreads();
    if (tid < 10) {
        float o = bc2[tid];
        #pragma unroll 8
        for (int j = 0; j < 64; j++) o += z[j] * Wc2[j * 10 + tid];
        outp[(size_t)g * 10 + tid] = o;
    }
}

// ---------------- launch ----------------

extern "C" void kernel_launch(void* const* d_in, const int* in_sizes, int n_in,
                              void* d_out, int out_size, void* d_ws, size_t ws_size,
                              hipStream_t stream) {
    const float* x      = (const float*)d_in[0];
    const int*   ei     = (const int*)d_in[1];
    const int*   batch  = (const int*)d_in[2];
    const float* W1 = (const float*)d_in[3];  const float* b1 = (const float*)d_in[4];
    const float* W2 = (const float*)d_in[5];  const float* b2 = (const float*)d_in[6];
    const float* W3 = (const float*)d_in[7];  const float* b3 = (const float*)d_in[8];
    const float* g1 = (const float*)d_in[9];  const float* be1 = (const float*)d_in[10];
    const float* g2 = (const float*)d_in[11]; const float* be2 = (const float*)d_in[12];
    const float* g3 = (const float*)d_in[13]; const float* be3 = (const float*)d_in[14];
    const float* Wc1 = (const float*)d_in[15]; const float* bc1 = (const float*)d_in[16];
    const float* Wc2 = (const float*)d_in[17]; const float* bc2 = (const float*)d_in[18];

    const int N = in_sizes[0] / 128;
    const int E = in_sizes[1] / 2;
    const int G = out_size / 10;
    const int* srcp = ei;
    const int* dstp = ei + E;

    // workspace layout
    char* ws = (char*)d_ws;
    size_t off = 0;
    float* bufA = (float*)(ws + off);  off += (size_t)N * 128 * 4;
    float* bufB = (float*)(ws + off);  off += (size_t)N * 128 * 4;
    int2*  csr  = (int2*)(ws + off);   off += (size_t)E * 8;
    int*   deg    = (int*)(ws + off);   off += (size_t)N * 4;
    float* dinv   = (float*)(ws + off); off += (size_t)N * 4;
    int*   rowptr = (int*)(ws + off);   off += (size_t)(N + 1) * 4;
    int*   cursor = (int*)(ws + off);   off += (size_t)N * 4;
    float* pooled = (float*)(ws + off); off += (size_t)G * 128 * 4;
    float* cnt    = (float*)(ws + off); off += (size_t)G * 4;
    int*   bsums  = (int*)(ws + off);   off += 256 * 4;
    (void)ws_size;

    int gN  = (N + 255) / 256;
    int gE  = (E + 255) / 256;
    int nb  = (N + 1023) / 1024;

    // graph structure
    k_init_deg<<<gN, 256, 0, stream>>>(deg, N);
    k_count<<<gE, 256, 0, stream>>>(dstp, deg, E);
    k_dinv<<<gN, 256, 0, stream>>>(deg, dinv, N);
    k_scan1<<<nb, 256, 0, stream>>>(deg, rowptr, bsums, N);
    k_scan2<<<1, 128, 0, stream>>>(bsums, nb);
    k_scan3<<<gN, 256, 0, stream>>>(rowptr, bsums, cursor, N, E);
    k_fill<<<gE, 256, 0, stream>>>(srcp, dstp, dinv, cursor, csr, E);

    int gGemm = (N + 63) / 64;
    int gAgg  = (N + 3) / 4;

    // layer 1
    k_gemm128<<<gGemm, 256, 0, stream>>>(x, W1, bufA, N);
    k_aggregate<<<gAgg, 256, 0, stream>>>(bufA, rowptr, csr, dinv, b1, g1, be1, bufB, N);
    // layer 2
    k_gemm128<<<gGemm, 256, 0, stream>>>(bufB, W2, bufA, N);
    k_aggregate<<<gAgg, 256, 0, stream>>>(bufA, rowptr, csr, dinv, b2, g2, be2, bufB, N);
    // layer 3
    k_gemm128<<<gGemm, 256, 0, stream>>>(bufB, W3, bufA, N);
    k_aggregate<<<gAgg, 256, 0, stream>>>(bufA, rowptr, csr, dinv, b3, g3, be3, bufB, N);

    // pooling
    hipMemsetAsync(pooled, 0, ((size_t)G * 128 + G) * 4, stream);
    int gPool = (N + 63) / 64;
    k_pool<<<gPool, 128, 0, stream>>>(bufB, batch, pooled, cnt, N);

    // classifier
    k_classifier<<<G, 64, 0, stream>>>(pooled, cnt, Wc1, bc1, Wc2, bc2, (float*)d_out, G);
}

// Round 3
// 620.071 us; speedup vs baseline: 1.8929x; 1.1913x over previous
//
#include <hip/hip_runtime.h>
#include <hip/hip_bf16.h>

#define INV1P 0.9999950000374997f

static __device__ __forceinline__ unsigned bf16rne(float f) {
    unsigned u = __float_as_uint(f);
    return (u + 0x7fffu + ((u >> 16) & 1u)) >> 16;
}

// ---------------- graph-structure kernels ----------------

__global__ __launch_bounds__(256) void k_init_deg(int* __restrict__ deg, int n) {
    int i = blockIdx.x * 256 + threadIdx.x;
    if (i < n) deg[i] = 1;  // self-loop
}

__global__ __launch_bounds__(256) void k_count(const int* __restrict__ dst, int* __restrict__ deg, int e) {
    int i = blockIdx.x * 256 + threadIdx.x;
    if (i < e) atomicAdd(&deg[dst[i]], 1);
}

__global__ __launch_bounds__(256) void k_dinv(const int* __restrict__ deg, float* __restrict__ dinv, int n) {
    int i = blockIdx.x * 256 + threadIdx.x;
    if (i < n) dinv[i] = rsqrtf((float)deg[i]);
}

// exclusive scan of (deg[i]-1) -> rowptr, in 3 stages. items/block = 1024.
__global__ __launch_bounds__(256) void k_scan1(const int* __restrict__ deg, int* __restrict__ part,
                                               int* __restrict__ bsums, int n) {
    __shared__ int sh[256];
    int tid = threadIdx.x;
    int base = blockIdx.x * 1024 + tid * 4;
    int v[4]; int s = 0;
    #pragma unroll
    for (int j = 0; j < 4; j++) {
        v[j] = (base + j < n) ? (deg[base + j] - 1) : 0;
        s += v[j];
    }
    sh[tid] = s; __syncthreads();
    for (int off = 1; off < 256; off <<= 1) {
        int t2 = (tid >= off) ? sh[tid - off] : 0;
        __syncthreads();
        sh[tid] += t2;
        __syncthreads();
    }
    int incl = sh[tid];
    int run = incl - s;  // exclusive for this thread's first item
    #pragma unroll
    for (int j = 0; j < 4; j++) {
        if (base + j < n) part[base + j] = run;
        run += v[j];
    }
    if (tid == 255) bsums[blockIdx.x] = incl;
}

__global__ __launch_bounds__(128) void k_scan2(int* __restrict__ bsums, int nb) {
    __shared__ int sh[128];
    int tid = threadIdx.x;
    int v = (tid < nb) ? bsums[tid] : 0;
    sh[tid] = v; __syncthreads();
    for (int off = 1; off < 128; off <<= 1) {
        int t2 = (tid >= off) ? sh[tid - off] : 0;
        __syncthreads();
        sh[tid] += t2;
        __syncthreads();
    }
    if (tid < nb) bsums[tid] = sh[tid] - v;  // exclusive
}

__global__ __launch_bounds__(256) void k_scan3(int* __restrict__ rowptr, const int* __restrict__ bsums,
                                               int* __restrict__ cursor, int n, int totalE) {
    int i = blockIdx.x * 256 + threadIdx.x;
    if (i < n) {
        int vv = rowptr[i] + bsums[i >> 10];
        rowptr[i] = vv;
        cursor[i] = vv;
    }
    if (i == 0) rowptr[n] = totalE;
}

__global__ __launch_bounds__(256) void k_fill(const int* __restrict__ src, const int* __restrict__ dst,
                                              const float* __restrict__ dinv, int* __restrict__ cursor,
                                              int2* __restrict__ csr, int e) {
    int i = blockIdx.x * 256 + threadIdx.x;
    if (i < e) {
        int s = src[i], d = dst[i];
        int slot = atomicAdd(&cursor[d], 1);
        csr[slot] = make_int2(s, __float_as_int(dinv[s] * dinv[d]));
    }
}

// ---------------- dense kernels ----------------

// Y[n,128](bf16) = X[n,128](fp32) @ W[128,128](fp32).
// 64-row x 128-col tile per 256-thread block; each thread: 8 rows x 4 cols.
__global__ __launch_bounds__(256, 4) void k_gemm128(const float* __restrict__ X, const float* __restrict__ W,
                                                    unsigned* __restrict__ Y, int nrows) {
    __shared__ float xs[64][128];
    int tid = threadIdx.x;
    int rowbase = blockIdx.x * 64;
    {
        const float4* X4 = (const float4*)X;
        #pragma unroll
        for (int i = 0; i < 8; i++) {
            int idx = tid + i * 256;          // 0..2047
            int r = idx >> 5, q = idx & 31;
            int gr = rowbase + r;
            float4 v = make_float4(0.f, 0.f, 0.f, 0.f);
            if (gr < nrows) v = X4[(size_t)gr * 32 + q];
            ((float4*)&xs[r][0])[q] = v;
        }
    }
    __syncthreads();
    int cq = tid & 31;    // col quad: cols cq*4..cq*4+3
    int rg = tid >> 5;    // row group: rows rg*8..rg*8+7
    const float4* W4 = (const float4*)W;
    float4 acc[8];
    #pragma unroll
    for (int r = 0; r < 8; r++) acc[r] = make_float4(0.f, 0.f, 0.f, 0.f);
    #pragma unroll 2
    for (int k4 = 0; k4 < 32; k4++) {
        float4 wv0 = W4[(k4 * 4 + 0) * 32 + cq];
        float4 wv1 = W4[(k4 * 4 + 1) * 32 + cq];
        float4 wv2 = W4[(k4 * 4 + 2) * 32 + cq];
        float4 wv3 = W4[(k4 * 4 + 3) * 32 + cq];
        #pragma unroll
        for (int r = 0; r < 8; r++) {
            float4 av = *((const float4*)&xs[rg * 8 + r][k4 * 4]);
            acc[r].x += av.x * wv0.x + av.y * wv1.x + av.z * wv2.x + av.w * wv3.x;
            acc[r].y += av.x * wv0.y + av.y * wv1.y + av.z * wv2.y + av.w * wv3.y;
            acc[r].z += av.x * wv0.z + av.y * wv1.z + av.z * wv2.z + av.w * wv3.z;
            acc[r].w += av.x * wv0.w + av.y * wv1.w + av.z * wv2.w + av.w * wv3.w;
        }
    }
    #pragma unroll
    for (int r = 0; r < 8; r++) {
        int grow = rowbase + rg * 8 + r;
        if (grow < nrows) {
            unsigned p0 = bf16rne(acc[r].x) | (bf16rne(acc[r].y) << 16);
            unsigned p1 = bf16rne(acc[r].z) | (bf16rne(acc[r].w) << 16);
            ((uint2*)Y)[(size_t)grow * 32 + cq] = make_uint2(p0, p1);
        }
    }
}

// out[node] = relu(bn(segsum + bias)); one node per wave.
// Hpre is bf16 (2 per uint); accumulate fp32; out fp32.
__global__ __launch_bounds__(256) void k_aggregate(const unsigned* __restrict__ Hpre, const int* __restrict__ rowptr,
                                                   const int2* __restrict__ csr,
                                                   const float* __restrict__ dinv,
                                                   const float* __restrict__ bias, const float* __restrict__ gamma,
                                                   const float* __restrict__ beta,
                                                   float* __restrict__ out, int nnodes) {
    int lane = threadIdx.x & 63;
    int node = blockIdx.x * 4 + (threadIdx.x >> 6);
    if (node >= nnodes) return;
    float di = dinv[node];
    float sl = di * di;
    unsigned hv = Hpre[(size_t)node * 64 + lane];
    float ax = __uint_as_float(hv << 16) * sl;
    float ay = __uint_as_float(hv & 0xffff0000u) * sl;
    int s = rowptr[node], e = rowptr[node + 1];
    int j = s;
    for (; j + 7 < e; j += 8) {
        int2 ee[8];
        #pragma unroll
        for (int q = 0; q < 8; q++) ee[q] = csr[j + q];
        unsigned vv[8];
        #pragma unroll
        for (int q = 0; q < 8; q++) vv[q] = Hpre[(size_t)(unsigned)ee[q].x * 64 + lane];
        #pragma unroll
        for (int q = 0; q < 8; q++) {
            float n = __int_as_float(ee[q].y);
            ax = fmaf(__uint_as_float(vv[q] << 16), n, ax);
            ay = fmaf(__uint_as_float(vv[q] & 0xffff0000u), n, ay);
        }
    }
    for (; j < e; j++) {
        int2 e0 = csr[j];
        unsigned v = Hpre[(size_t)(unsigned)e0.x * 64 + lane];
        float n = __int_as_float(e0.y);
        ax = fmaf(__uint_as_float(v << 16), n, ax);
        ay = fmaf(__uint_as_float(v & 0xffff0000u), n, ay);
    }
    float2 bi = ((const float2*)bias)[lane];
    float2 ga = ((const float2*)gamma)[lane];
    float2 be = ((const float2*)beta)[lane];
    float vx = fmaf(ga.x * INV1P, ax + bi.x, be.x);
    float vy = fmaf(ga.y * INV1P, ay + bi.y, be.y);
    float2 res = make_float2(fmaxf(vx, 0.f), fmaxf(vy, 0.f));
    ((float2*)out)[(size_t)node * 64 + lane] = res;
}

// pooled sums: 64 consecutive nodes per 128-thread block; batch sorted.
__global__ __launch_bounds__(128) void k_pool(const float* __restrict__ Hf, const int* __restrict__ batch,
                                              float* __restrict__ pooled, float* __restrict__ cnt, int nnodes) {
    int t = threadIdx.x;
    int base = blockIdx.x * 64;
    if (base >= nnodes) return;
    int end = min(base + 64, nnodes);
    float acc = 0.f; int run = 0;
    int cur = batch[base];
    for (int i = base; i < end; i++) {
        int bg = batch[i];
        if (bg != cur) {
            atomicAdd(&pooled[(size_t)cur * 128 + t], acc);
            if (t == 0) atomicAdd(&cnt[cur], (float)run);
            acc = 0.f; run = 0; cur = bg;
        }
        acc += Hf[(size_t)i * 128 + t];
        run++;
    }
    atomicAdd(&pooled[(size_t)cur * 128 + t], acc);
    if (t == 0) atomicAdd(&cnt[cur], (float)run);
}

// classifier: one 64-thread block per graph. 128 -> 64 (relu) -> 10
__global__ __launch_bounds__(64) void k_classifier(const float* __restrict__ pooled, const float* __restrict__ cnt,
                                                   const float* __restrict__ Wc1, const float* __restrict__ bc1,
                                                   const float* __restrict__ Wc2, const float* __restrict__ bc2,
                                                   float* __restrict__ outp, int ngraphs) {
    __shared__ float p[128];
    __shared__ float z[64];
    int g = blockIdx.x;
    int tid = threadIdx.x;
    float inv = 1.0f / fmaxf(cnt[g], 1.0f);
    p[tid]      = pooled[(size_t)g * 128 + tid] * inv;
    p[tid + 64] = pooled[(size_t)g * 128 + 64 + tid] * inv;
    __syncthreads();
    float a = bc1[tid];
    #pragma unroll 8
    for (int k = 0; k < 128; k++) a += p[k] * Wc1[k * 64 + tid];
    z[tid] = fmaxf(a, 0.f);
    __syncthreads();
    if (tid < 10) {
        float o = bc2[tid];
        #pragma unroll 8
        for (int j = 0; j < 64; j++) o += z[j] * Wc2[j * 10 + tid];
        outp[(size_t)g * 10 + tid] = o;
    }
}

// ---------------- launch ----------------

extern "C" void kernel_launch(void* const* d_in, const int* in_sizes, int n_in,
                              void* d_out, int out_size, void* d_ws, size_t ws_size,
                              hipStream_t stream) {
    const float* x      = (const float*)d_in[0];
    const int*   ei     = (const int*)d_in[1];
    const int*   batch  = (const int*)d_in[2];
    const float* W1 = (const float*)d_in[3];  const float* b1 = (const float*)d_in[4];
    const float* W2 = (const float*)d_in[5];  const float* b2 = (const float*)d_in[6];
    const float* W3 = (const float*)d_in[7];  const float* b3 = (const float*)d_in[8];
    const float* g1 = (const float*)d_in[9];  const float* be1 = (const float*)d_in[10];
    const float* g2 = (const float*)d_in[11]; const float* be2 = (const float*)d_in[12];
    const float* g3 = (const float*)d_in[13]; const float* be3 = (const float*)d_in[14];
    const float* Wc1 = (const float*)d_in[15]; const float* bc1 = (const float*)d_in[16];
    const float* Wc2 = (const float*)d_in[17]; const float* bc2 = (const float*)d_in[18];

    const int N = in_sizes[0] / 128;
    const int E = in_sizes[1] / 2;
    const int G = out_size / 10;
    const int* srcp = ei;
    const int* dstp = ei + E;

    // workspace layout
    char* ws = (char*)d_ws;
    size_t off = 0;
    unsigned* bufA = (unsigned*)(ws + off); off += (size_t)N * 64 * 4;   // bf16 H, 2/uint
    float* bufB = (float*)(ws + off);  off += (size_t)N * 128 * 4;
    int2*  csr  = (int2*)(ws + off);   off += (size_t)E * 8;
    int*   deg    = (int*)(ws + off);   off += (size_t)N * 4;
    float* dinv   = (float*)(ws + off); off += (size_t)N * 4;
    int*   rowptr = (int*)(ws + off);   off += (size_t)(N + 1) * 4;
    int*   cursor = (int*)(ws + off);   off += (size_t)N * 4;
    float* pooled = (float*)(ws + off); off += (size_t)G * 128 * 4;
    float* cnt    = (float*)(ws + off); off += (size_t)G * 4;
    int*   bsums  = (int*)(ws + off);   off += 256 * 4;
    (void)ws_size;

    int gN  = (N + 255) / 256;
    int gE  = (E + 255) / 256;
    int nb  = (N + 1023) / 1024;

    // graph structure
    k_init_deg<<<gN, 256, 0, stream>>>(deg, N);
    k_count<<<gE, 256, 0, stream>>>(dstp, deg, E);
    k_dinv<<<gN, 256, 0, stream>>>(deg, dinv, N);
    k_scan1<<<nb, 256, 0, stream>>>(deg, rowptr, bsums, N);
    k_scan2<<<1, 128, 0, stream>>>(bsums, nb);
    k_scan3<<<gN, 256, 0, stream>>>(rowptr, bsums, cursor, N, E);
    k_fill<<<gE, 256, 0, stream>>>(srcp, dstp, dinv, cursor, csr, E);

    int gGemm = (N + 63) / 64;
    int gAgg  = (N + 3) / 4;

    // layer 1
    k_gemm128<<<gGemm, 256, 0, stream>>>(x, W1, bufA, N);
    k_aggregate<<<gAgg, 256, 0, stream>>>(bufA, rowptr, csr, dinv, b1, g1, be1, bufB, N);
    // layer 2
    k_gemm128<<<gGemm, 256, 0, stream>>>(bufB, W2, bufA, N);
    k_aggregate<<<gAgg, 256, 0, stream>>>(bufA, rowptr, csr, dinv, b2, g2, be2, bufB, N);
    // layer 3
    k_gemm128<<<gGemm, 256, 0, stream>>>(bufB, W3, bufA, N);
    k_aggregate<<<gAgg, 256, 0, stream>>>(bufA, rowptr, csr, dinv, b3, g3, be3, bufB, N);

    // pooling
    hipMemsetAsync(pooled, 0, ((size_t)G * 128 + G) * 4, stream);
    int gPool = (N + 63) / 64;
    k_pool<<<gPool, 128, 0, stream>>>(bufB, batch, pooled, cnt, N);

    // classifier
    k_classifier<<<G, 64, 0, stream>>>(pooled, cnt, Wc1, bc1, Wc2, bc2, (float*)d_out, G);
}

// Round 4
// 524.504 us; speedup vs baseline: 2.2379x; 1.1822x over previous
//
#include <hip/hip_runtime.h>
#include <hip/hip_bf16.h>

#define INV1P 0.9999950000374997f

typedef __attribute__((ext_vector_type(8))) short bfrag;   // 8 x bf16 (4 VGPR)
typedef __attribute__((ext_vector_type(4))) float f32x4;   // MFMA accumulator

static __device__ __forceinline__ unsigned bf16rne(float f) {
    unsigned u = __float_as_uint(f);
    return (u + 0x7fffu + ((u >> 16) & 1u)) >> 16;
}

// ---------------- graph-structure kernels ----------------

__global__ __launch_bounds__(256) void k_init_deg(int* __restrict__ deg, int n) {
    int i = blockIdx.x * 256 + threadIdx.x;
    if (i < n) deg[i] = 1;  // self-loop
}

__global__ __launch_bounds__(256) void k_count(const int* __restrict__ dst, int* __restrict__ deg, int e) {
    int i = blockIdx.x * 256 + threadIdx.x;
    if (i < e) atomicAdd(&deg[dst[i]], 1);
}

__global__ __launch_bounds__(256) void k_dinv(const int* __restrict__ deg, float* __restrict__ dinv, int n) {
    int i = blockIdx.x * 256 + threadIdx.x;
    if (i < n) dinv[i] = rsqrtf((float)deg[i]);
}

// exclusive scan of (deg[i]-1) -> rowptr, in 3 stages. items/block = 1024.
__global__ __launch_bounds__(256) void k_scan1(const int* __restrict__ deg, int* __restrict__ part,
                                               int* __restrict__ bsums, int n) {
    __shared__ int sh[256];
    int tid = threadIdx.x;
    int base = blockIdx.x * 1024 + tid * 4;
    int v[4]; int s = 0;
    #pragma unroll
    for (int j = 0; j < 4; j++) {
        v[j] = (base + j < n) ? (deg[base + j] - 1) : 0;
        s += v[j];
    }
    sh[tid] = s; __syncthreads();
    for (int off = 1; off < 256; off <<= 1) {
        int t2 = (tid >= off) ? sh[tid - off] : 0;
        __syncthreads();
        sh[tid] += t2;
        __syncthreads();
    }
    int incl = sh[tid];
    int run = incl - s;
    #pragma unroll
    for (int j = 0; j < 4; j++) {
        if (base + j < n) part[base + j] = run;
        run += v[j];
    }
    if (tid == 255) bsums[blockIdx.x] = incl;
}

__global__ __launch_bounds__(128) void k_scan2(int* __restrict__ bsums, int nb) {
    __shared__ int sh[128];
    int tid = threadIdx.x;
    int v = (tid < nb) ? bsums[tid] : 0;
    sh[tid] = v; __syncthreads();
    for (int off = 1; off < 128; off <<= 1) {
        int t2 = (tid >= off) ? sh[tid - off] : 0;
        __syncthreads();
        sh[tid] += t2;
        __syncthreads();
    }
    if (tid < nb) bsums[tid] = sh[tid] - v;
}

__global__ __launch_bounds__(256) void k_scan3(int* __restrict__ rowptr, const int* __restrict__ bsums,
                                               int* __restrict__ cursor, int n, int totalE) {
    int i = blockIdx.x * 256 + threadIdx.x;
    if (i < n) {
        int vv = rowptr[i] + bsums[i >> 10];
        rowptr[i] = vv;
        cursor[i] = vv;
    }
    if (i == 0) rowptr[n] = totalE;
}

__global__ __launch_bounds__(256) void k_fill(const int* __restrict__ src, const int* __restrict__ dst,
                                              int* __restrict__ cursor,
                                              int* __restrict__ csr_src, int e) {
    int i = blockIdx.x * 256 + threadIdx.x;
    if (i < e) {
        int s = src[i], d = dst[i];
        int slot = atomicAdd(&cursor[d], 1);
        csr_src[slot] = s;
    }
}

// ---------------- dense kernels ----------------

// fp32 -> packed bf16 convert (for layer-1 X). one float4 -> uint2 per thread.
__global__ __launch_bounds__(256) void k_cvt(const float* __restrict__ x, unsigned* __restrict__ xb, int n4) {
    int i = blockIdx.x * 256 + threadIdx.x;
    if (i >= n4) return;
    float4 v = ((const float4*)x)[i];
    unsigned p0 = bf16rne(v.x) | (bf16rne(v.y) << 16);
    unsigned p1 = bf16rne(v.z) | (bf16rne(v.w) << 16);
    ((uint2*)xb)[i] = make_uint2(p0, p1);
}

// Build MFMA B-operand fragments from fp32 W[128][128] (row-major, W[k][n]).
// Layout: Bf[part][e][lane], e = kk*8+c (kk=k-step, c=col-tile), 16B per entry.
// part 0 = bf16_hi(W), part 1 = bf16(W - hi)  (split for accuracy).
__global__ __launch_bounds__(256) void k_prepw(const float* __restrict__ W, uint4* __restrict__ Bf) {
    int id = blockIdx.x * 256 + threadIdx.x;   // 0..2047
    int lane = id & 63;
    int e = id >> 6;                            // 0..31
    int kk = e >> 3, c = e & 7;
    int kbase = kk * 32 + (lane >> 4) * 8;
    int col = c * 16 + (lane & 15);
    unsigned hi[8], lo[8];
    #pragma unroll
    for (int j = 0; j < 8; j++) {
        float w = W[(kbase + j) * 128 + col];
        unsigned h = bf16rne(w);
        float rh = __uint_as_float(h << 16);
        unsigned l = bf16rne(w - rh);
        hi[j] = h; lo[j] = l;
    }
    uint4 H = make_uint4(hi[0] | (hi[1] << 16), hi[2] | (hi[3] << 16),
                         hi[4] | (hi[5] << 16), hi[6] | (hi[7] << 16));
    uint4 L = make_uint4(lo[0] | (lo[1] << 16), lo[2] | (lo[3] << 16),
                         lo[4] | (lo[5] << 16), lo[6] | (lo[7] << 16));
    Bf[e * 64 + lane] = H;
    Bf[2048 + e * 64 + lane] = L;
}

// Y[n,128](bf16) = X[n,128](bf16) @ (Whi+Wlo). MFMA 16x16x32, fp32 accum.
// 512 threads = 8 waves; 16 rows/wave -> 128 rows/block.
__global__ __launch_bounds__(512) void k_gemm_mfma(const unsigned* __restrict__ Xb,
                                                   const uint4* __restrict__ Bfr,
                                                   unsigned* __restrict__ Y, int nrows) {
    __shared__ uint4 bs[4096];                 // [2][32][64] b-frags = 64 KB
    int tid = threadIdx.x;
    int w = tid >> 6, lane = tid & 63;
    int rowbase = blockIdx.x * 128;

    // stage b-frags (both parts) into LDS
    #pragma unroll
    for (int i = 0; i < 8; i++) {
        int idx = tid + i * 512;
        bs[idx] = Bfr[idx];
    }

    // load A fragments direct from global (no reuse across waves)
    int row = rowbase + w * 16 + (lane & 15);
    int rowc = min(row, nrows - 1);
    const uint4* X4 = (const uint4*)Xb;
    bfrag a[4];
    #pragma unroll
    for (int kk = 0; kk < 4; kk++) {
        uint4 av = X4[(size_t)rowc * 16 + kk * 4 + (lane >> 4)];
        a[kk] = *(const bfrag*)&av;
    }
    __syncthreads();

    f32x4 acc[8];
    #pragma unroll
    for (int c = 0; c < 8; c++) acc[c] = (f32x4){0.f, 0.f, 0.f, 0.f};

    #pragma unroll
    for (int kk = 0; kk < 4; kk++) {
        #pragma unroll
        for (int c = 0; c < 8; c++) {
            bfrag bh = *(const bfrag*)&bs[(kk * 8 + c) * 64 + lane];
            bfrag bl = *(const bfrag*)&bs[2048 + (kk * 8 + c) * 64 + lane];
            acc[c] = __builtin_amdgcn_mfma_f32_16x16x32_bf16(a[kk], bh, acc[c], 0, 0, 0);
            acc[c] = __builtin_amdgcn_mfma_f32_16x16x32_bf16(a[kk], bl, acc[c], 0, 0, 0);
        }
    }

    // epilogue: bounce through LDS (per-wave 16 x 136 ushorts) -> coalesced stores
    __syncthreads();   // all waves done reading bs
    char* epib = (char*)bs;
    ushort* epi = (ushort*)(epib + w * 4352);
    #pragma unroll
    for (int c = 0; c < 8; c++) {
        #pragma unroll
        for (int r = 0; r < 4; r++) {
            int rr = (lane >> 4) * 4 + r;
            epi[rr * 136 + c * 16 + (lane & 15)] = (ushort)bf16rne(acc[c][r]);
        }
    }
    __syncthreads();
    #pragma unroll
    for (int i = 0; i < 4; i++) {
        int id = tid + i * 512;      // 0..2047
        int rr = id >> 4, q = id & 15;
        int grow = rowbase + rr;
        if (grow < nrows) {
            uint4 v = *(const uint4*)(epib + (rr >> 4) * 4352 + (rr & 15) * 272 + q * 16);
            ((uint4*)Y)[(size_t)grow * 16 + q] = v;
        }
    }
}

// out[node](bf16) = relu(bn(segsum + bias)); one node per wave; fp32 accum.
__global__ __launch_bounds__(256) void k_aggregate(const unsigned* __restrict__ Hpre, const int* __restrict__ rowptr,
                                                   const int* __restrict__ csr_src,
                                                   const float* __restrict__ dinv,
                                                   const float* __restrict__ bias, const float* __restrict__ gamma,
                                                   const float* __restrict__ beta,
                                                   unsigned* __restrict__ out, int nnodes) {
    int lane = threadIdx.x & 63;
    int node = blockIdx.x * 4 + (threadIdx.x >> 6);
    if (node >= nnodes) return;
    float dn = dinv[node];
    unsigned hv = Hpre[(size_t)node * 64 + lane];
    float sl = dn * dn;
    float ax = __uint_as_float(hv << 16) * sl;
    float ay = __uint_as_float(hv & 0xffff0000u) * sl;
    int s = rowptr[node], e = rowptr[node + 1];
    int j = s;
    for (; j + 7 < e; j += 8) {
        int ss[8];
        #pragma unroll
        for (int q = 0; q < 8; q++) ss[q] = csr_src[j + q];
        float nn[8];
        #pragma unroll
        for (int q = 0; q < 8; q++) nn[q] = dinv[ss[q]] * dn;
        unsigned vv[8];
        #pragma unroll
        for (int q = 0; q < 8; q++) vv[q] = Hpre[(size_t)(unsigned)ss[q] * 64 + lane];
        #pragma unroll
        for (int q = 0; q < 8; q++) {
            ax = fmaf(__uint_as_float(vv[q] << 16), nn[q], ax);
            ay = fmaf(__uint_as_float(vv[q] & 0xffff0000u), nn[q], ay);
        }
    }
    for (; j < e; j++) {
        int s0 = csr_src[j];
        float n = dinv[s0] * dn;
        unsigned v = Hpre[(size_t)(unsigned)s0 * 64 + lane];
        ax = fmaf(__uint_as_float(v << 16), n, ax);
        ay = fmaf(__uint_as_float(v & 0xffff0000u), n, ay);
    }
    float2 bi = ((const float2*)bias)[lane];
    float2 ga = ((const float2*)gamma)[lane];
    float2 be = ((const float2*)beta)[lane];
    float vx = fmaf(ga.x * INV1P, ax + bi.x, be.x);
    float vy = fmaf(ga.y * INV1P, ay + bi.y, be.y);
    vx = fmaxf(vx, 0.f);
    vy = fmaxf(vy, 0.f);
    out[(size_t)node * 64 + lane] = bf16rne(vx) | (bf16rne(vy) << 16);
}

// pooled sums from bf16 H: 64 consecutive nodes per 64-thread block; batch sorted.
__global__ __launch_bounds__(64) void k_pool(const unsigned* __restrict__ Hf, const int* __restrict__ batch,
                                             float* __restrict__ pooled, float* __restrict__ cnt, int nnodes) {
    int t = threadIdx.x;   // 0..63, col pair t -> cols 2t, 2t+1
    int base = blockIdx.x * 64;
    if (base >= nnodes) return;
    int end = min(base + 64, nnodes);
    float ax = 0.f, ay = 0.f; int run = 0;
    int cur = batch[base];
    for (int i = base; i < end; i++) {
        int bg = batch[i];
        if (bg != cur) {
            atomicAdd(&pooled[(size_t)cur * 128 + 2 * t], ax);
            atomicAdd(&pooled[(size_t)cur * 128 + 2 * t + 1], ay);
            if (t == 0) atomicAdd(&cnt[cur], (float)run);
            ax = 0.f; ay = 0.f; run = 0; cur = bg;
        }
        unsigned u = Hf[(size_t)i * 64 + t];
        ax += __uint_as_float(u << 16);
        ay += __uint_as_float(u & 0xffff0000u);
        run++;
    }
    atomicAdd(&pooled[(size_t)cur * 128 + 2 * t], ax);
    atomicAdd(&pooled[(size_t)cur * 128 + 2 * t + 1], ay);
    if (t == 0) atomicAdd(&cnt[cur], (float)run);
}

// classifier: one 64-thread block per graph. 128 -> 64 (relu) -> 10
__global__ __launch_bounds__(64) void k_classifier(const float* __restrict__ pooled, const float* __restrict__ cnt,
                                                   const float* __restrict__ Wc1, const float* __restrict__ bc1,
                                                   const float* __restrict__ Wc2, const float* __restrict__ bc2,
                                                   float* __restrict__ outp, int ngraphs) {
    __shared__ float p[128];
    __shared__ float z[64];
    int g = blockIdx.x;
    int tid = threadIdx.x;
    float inv = 1.0f / fmaxf(cnt[g], 1.0f);
    p[tid]      = pooled[(size_t)g * 128 + tid] * inv;
    p[tid + 64] = pooled[(size_t)g * 128 + 64 + tid] * inv;
    __syncthreads();
    float a = bc1[tid];
    #pragma unroll 8
    for (int k = 0; k < 128; k++) a += p[k] * Wc1[k * 64 + tid];
    z[tid] = fmaxf(a, 0.f);
    __syncthreads();
    if (tid < 10) {
        float o = bc2[tid];
        #pragma unroll 8
        for (int j = 0; j < 64; j++) o += z[j] * Wc2[j * 10 + tid];
        outp[(size_t)g * 10 + tid] = o;
    }
}

// ---------------- launch ----------------

static inline size_t align16(size_t v) { return (v + 15) & ~(size_t)15; }

extern "C" void kernel_launch(void* const* d_in, const int* in_sizes, int n_in,
                              void* d_out, int out_size, void* d_ws, size_t ws_size,
                              hipStream_t stream) {
    const float* x      = (const float*)d_in[0];
    const int*   ei     = (const int*)d_in[1];
    const int*   batch  = (const int*)d_in[2];
    const float* W1 = (const float*)d_in[3];  const float* b1 = (const float*)d_in[4];
    const float* W2 = (const float*)d_in[5];  const float* b2 = (const float*)d_in[6];
    const float* W3 = (const float*)d_in[7];  const float* b3 = (const float*)d_in[8];
    const float* g1 = (const float*)d_in[9];  const float* be1 = (const float*)d_in[10];
    const float* g2 = (const float*)d_in[11]; const float* be2 = (const float*)d_in[12];
    const float* g3 = (const float*)d_in[13]; const float* be3 = (const float*)d_in[14];
    const float* Wc1 = (const float*)d_in[15]; const float* bc1 = (const float*)d_in[16];
    const float* Wc2 = (const float*)d_in[17]; const float* bc2 = (const float*)d_in[18];

    const int N = in_sizes[0] / 128;
    const int E = in_sizes[1] / 2;
    const int G = out_size / 10;
    const int* srcp = ei;
    const int* dstp = ei + E;

    // workspace layout (16B-aligned slots)
    char* ws = (char*)d_ws;
    size_t off = 0;
    unsigned* bufA = (unsigned*)(ws + off); off = align16(off + (size_t)N * 64 * 4);
    unsigned* bufB = (unsigned*)(ws + off); off = align16(off + (size_t)N * 64 * 4);
    unsigned* xb   = (unsigned*)(ws + off); off = align16(off + (size_t)N * 64 * 4);
    uint4* Bfr1 = (uint4*)(ws + off); off = align16(off + 4096 * 16);
    uint4* Bfr2 = (uint4*)(ws + off); off = align16(off + 4096 * 16);
    uint4* Bfr3 = (uint4*)(ws + off); off = align16(off + 4096 * 16);
    int*   csr_src = (int*)(ws + off);  off = align16(off + (size_t)E * 4);
    int*   deg    = (int*)(ws + off);   off = align16(off + (size_t)N * 4);
    float* dinv   = (float*)(ws + off); off = align16(off + (size_t)N * 4);
    int*   rowptr = (int*)(ws + off);   off = align16(off + (size_t)(N + 1) * 4);
    int*   cursor = (int*)(ws + off);   off = align16(off + (size_t)N * 4);
    float* pooled = (float*)(ws + off); off = align16(off + (size_t)G * 128 * 4);
    float* cnt    = (float*)(ws + off); off = align16(off + (size_t)G * 4);
    int*   bsums  = (int*)(ws + off);   off = align16(off + 256 * 4);
    (void)ws_size;

    int gN  = (N + 255) / 256;
    int gE  = (E + 255) / 256;
    int nb  = (N + 1023) / 1024;

    // input conversion + weight prep (independent of graph structure)
    k_cvt<<<(N * 32 + 255) / 256, 256, 0, stream>>>(x, xb, N * 32);
    k_prepw<<<8, 256, 0, stream>>>(W1, Bfr1);
    k_prepw<<<8, 256, 0, stream>>>(W2, Bfr2);
    k_prepw<<<8, 256, 0, stream>>>(W3, Bfr3);

    // graph structure
    k_init_deg<<<gN, 256, 0, stream>>>(deg, N);
    k_count<<<gE, 256, 0, stream>>>(dstp, deg, E);
    k_dinv<<<gN, 256, 0, stream>>>(deg, dinv, N);
    k_scan1<<<nb, 256, 0, stream>>>(deg, rowptr, bsums, N);
    k_scan2<<<1, 128, 0, stream>>>(bsums, nb);
    k_scan3<<<gN, 256, 0, stream>>>(rowptr, bsums, cursor, N, E);
    k_fill<<<gE, 256, 0, stream>>>(srcp, dstp, cursor, csr_src, E);

    int gGemm = (N + 127) / 128;
    int gAgg  = (N + 3) / 4;

    // layer 1
    k_gemm_mfma<<<gGemm, 512, 0, stream>>>(xb, Bfr1, bufA, N);
    k_aggregate<<<gAgg, 256, 0, stream>>>(bufA, rowptr, csr_src, dinv, b1, g1, be1, bufB, N);
    // layer 2
    k_gemm_mfma<<<gGemm, 512, 0, stream>>>(bufB, Bfr2, bufA, N);
    k_aggregate<<<gAgg, 256, 0, stream>>>(bufA, rowptr, csr_src, dinv, b2, g2, be2, bufB, N);
    // layer 3
    k_gemm_mfma<<<gGemm, 512, 0, stream>>>(bufB, Bfr3, bufA, N);
    k_aggregate<<<gAgg, 256, 0, stream>>>(bufA, rowptr, csr_src, dinv, b3, g3, be3, bufB, N);

    // pooling
    hipMemsetAsync(pooled, 0, ((size_t)G * 128 + G) * 4, stream);
    int gPool = (N + 63) / 64;
    k_pool<<<gPool, 64, 0, stream>>>(bufB, batch, pooled, cnt, N);

    // classifier
    k_classifier<<<G, 64, 0, stream>>>(pooled, cnt, Wc1, bc1, Wc2, bc2, (float*)d_out, G);
}

// Round 5
// 436.912 us; speedup vs baseline: 2.6865x; 1.2005x over previous
//
#include <hip/hip_runtime.h>
#include <hip/hip_bf16.h>

#define INV1P 0.9999950000374997f

typedef __attribute__((ext_vector_type(8))) short bfrag;   // 8 x bf16 (4 VGPR)
typedef __attribute__((ext_vector_type(4))) float f32x4;   // MFMA accumulator

static __device__ __forceinline__ unsigned bf16rne(float f) {
    unsigned u = __float_as_uint(f);
    return (u + 0x7fffu + ((u >> 16) & 1u)) >> 16;
}

// ---------------- graph-structure kernels ----------------

__global__ __launch_bounds__(256) void k_init_deg(int* __restrict__ deg, int n) {
    int i = blockIdx.x * 256 + threadIdx.x;
    if (i < n) deg[i] = 1;  // self-loop
}

__global__ __launch_bounds__(256) void k_count(const int* __restrict__ dst, int* __restrict__ deg, int e) {
    int i = blockIdx.x * 256 + threadIdx.x;
    if (i < e) atomicAdd(&deg[dst[i]], 1);
}

__global__ __launch_bounds__(256) void k_dinv(const int* __restrict__ deg, float* __restrict__ dinv, int n) {
    int i = blockIdx.x * 256 + threadIdx.x;
    if (i < n) dinv[i] = rsqrtf((float)deg[i]);
}

// exclusive scan of (deg[i]-1) -> rowptr, in 3 stages. items/block = 1024.
__global__ __launch_bounds__(256) void k_scan1(const int* __restrict__ deg, int* __restrict__ part,
                                               int* __restrict__ bsums, int n) {
    __shared__ int sh[256];
    int tid = threadIdx.x;
    int base = blockIdx.x * 1024 + tid * 4;
    int v[4]; int s = 0;
    #pragma unroll
    for (int j = 0; j < 4; j++) {
        v[j] = (base + j < n) ? (deg[base + j] - 1) : 0;
        s += v[j];
    }
    sh[tid] = s; __syncthreads();
    for (int off = 1; off < 256; off <<= 1) {
        int t2 = (tid >= off) ? sh[tid - off] : 0;
        __syncthreads();
        sh[tid] += t2;
        __syncthreads();
    }
    int incl = sh[tid];
    int run = incl - s;
    #pragma unroll
    for (int j = 0; j < 4; j++) {
        if (base + j < n) part[base + j] = run;
        run += v[j];
    }
    if (tid == 255) bsums[blockIdx.x] = incl;
}

__global__ __launch_bounds__(128) void k_scan2(int* __restrict__ bsums, int nb) {
    __shared__ int sh[128];
    int tid = threadIdx.x;
    int v = (tid < nb) ? bsums[tid] : 0;
    sh[tid] = v; __syncthreads();
    for (int off = 1; off < 128; off <<= 1) {
        int t2 = (tid >= off) ? sh[tid - off] : 0;
        __syncthreads();
        sh[tid] += t2;
        __syncthreads();
    }
    if (tid < nb) bsums[tid] = sh[tid] - v;
}

__global__ __launch_bounds__(256) void k_scan3(int* __restrict__ rowptr, const int* __restrict__ bsums,
                                               int n, int totalE) {
    int i = blockIdx.x * 256 + threadIdx.x;
    if (i < n) rowptr[i] = rowptr[i] + bsums[i >> 10];
    if (i == 0) rowptr[n] = totalE;
}

// gcursor[b] = rowptr[512*b]  (bucket b covers nodes [512b, 512b+512))
__global__ __launch_bounds__(256) void k_initcur(const int* __restrict__ rowptr, int* __restrict__ gcursor, int nbuckets) {
    int b = threadIdx.x + blockIdx.x * 256;
    if (b < nbuckets) gcursor[b] = rowptr[b << 9];
}

// pass A: bin edges by dst-bucket. 8192 edges/block, packed (src | dst_low<<17).
__global__ __launch_bounds__(256) void k_binA(const int* __restrict__ src, const int* __restrict__ dst,
                                              int* __restrict__ gcursor, unsigned* __restrict__ binned, int e) {
    __shared__ unsigned pk[8192];
    __shared__ unsigned char bk[8192];
    __shared__ int hist[256];
    __shared__ int base[256];
    int tid = threadIdx.x;
    hist[tid] = 0;
    __syncthreads();
    int cbase = blockIdx.x * 8192;
    int cnt = min(8192, e - cbase);
    for (int j = tid; j < cnt; j += 256) {
        int s = src[cbase + j], d = dst[cbase + j];
        unsigned b = (unsigned)d >> 9;
        pk[j] = (unsigned)s | (((unsigned)d & 511u) << 17);
        bk[j] = (unsigned char)b;
        atomicAdd(&hist[b], 1);
    }
    __syncthreads();
    int h = hist[tid];
    base[tid] = (h > 0) ? atomicAdd(&gcursor[tid], h) : 0;
    hist[tid] = 0;
    __syncthreads();
    for (int j = tid; j < cnt; j += 256) {
        unsigned b = bk[j];
        int off = atomicAdd(&hist[b], 1);
        binned[base[b] + off] = pk[j];
    }
}

// pass B: one block per bucket; scatter binned entries into dense CSR order.
__global__ __launch_bounds__(256) void k_binB(const unsigned* __restrict__ binned, const int* __restrict__ rowptr,
                                              int* __restrict__ csr_src, int n) {
    __shared__ int rp[513];
    __shared__ int cur[512];
    int b = blockIdx.x, tid = threadIdx.x;
    int nstart = b << 9;
    int nend = min(nstart + 512, n);
    int nn = nend - nstart;
    for (int j = tid; j < nn + 1; j += 256) rp[j] = rowptr[nstart + j];
    for (int j = tid; j < nn; j += 256) cur[j] = 0;
    __syncthreads();
    int s0 = rp[0], s1 = rp[nn];
    for (int j = s0 + tid; j < s1; j += 256) {
        unsigned p = binned[j];
        int nl = (p >> 17) & 511;
        int sv = p & 0x1ffff;
        int idx = atomicAdd(&cur[nl], 1);
        csr_src[rp[nl] + idx] = sv;
    }
}

// ---------------- dense kernels ----------------

// Build MFMA B-operand fragments from fp32 W[128][128] (row-major, W[k][n]).
// part 0 = bf16_hi(W), part 1 = bf16(W - hi)  (split for accuracy).
__global__ __launch_bounds__(256) void k_prepw(const float* __restrict__ W, uint4* __restrict__ Bf) {
    int id = blockIdx.x * 256 + threadIdx.x;   // 0..2047
    int lane = id & 63;
    int e = id >> 6;                            // 0..31
    int kk = e >> 3, c = e & 7;
    int kbase = kk * 32 + (lane >> 4) * 8;
    int col = c * 16 + (lane & 15);
    unsigned hi[8], lo[8];
    #pragma unroll
    for (int j = 0; j < 8; j++) {
        float w = W[(kbase + j) * 128 + col];
        unsigned h = bf16rne(w);
        float rh = __uint_as_float(h << 16);
        unsigned l = bf16rne(w - rh);
        hi[j] = h; lo[j] = l;
    }
    uint4 H = make_uint4(hi[0] | (hi[1] << 16), hi[2] | (hi[3] << 16),
                         hi[4] | (hi[5] << 16), hi[6] | (hi[7] << 16));
    uint4 L = make_uint4(lo[0] | (lo[1] << 16), lo[2] | (lo[3] << 16),
                         lo[4] | (lo[5] << 16), lo[6] | (lo[7] << 16));
    Bf[e * 64 + lane] = H;
    Bf[2048 + e * 64 + lane] = L;
}

// common MFMA GEMM body: a[4] fragments already loaded.
// Y[n,128](bf16) = A @ (Whi+Wlo). 512 threads = 8 waves, 128 rows/block.
static __device__ __forceinline__ void gemm_body(const uint4* __restrict__ Bfr, unsigned* __restrict__ Y,
                                                 int nrows, int rowbase, bfrag* a, uint4* bs) {
    int tid = threadIdx.x;
    int w = tid >> 6, lane = tid & 63;
    __syncthreads();   // bs staged
    f32x4 acc[8];
    #pragma unroll
    for (int c = 0; c < 8; c++) acc[c] = (f32x4){0.f, 0.f, 0.f, 0.f};
    #pragma unroll
    for (int kk = 0; kk < 4; kk++) {
        #pragma unroll
        for (int c = 0; c < 8; c++) {
            bfrag bh = *(const bfrag*)&bs[(kk * 8 + c) * 64 + lane];
            bfrag bl = *(const bfrag*)&bs[2048 + (kk * 8 + c) * 64 + lane];
            acc[c] = __builtin_amdgcn_mfma_f32_16x16x32_bf16(a[kk], bh, acc[c], 0, 0, 0);
            acc[c] = __builtin_amdgcn_mfma_f32_16x16x32_bf16(a[kk], bl, acc[c], 0, 0, 0);
        }
    }
    // epilogue: bounce through LDS (per-wave 16 x 136 ushorts) -> coalesced stores
    __syncthreads();
    char* epib = (char*)bs;
    ushort* epi = (ushort*)(epib + w * 4352);
    #pragma unroll
    for (int c = 0; c < 8; c++) {
        #pragma unroll
        for (int r = 0; r < 4; r++) {
            int rr = (lane >> 4) * 4 + r;
            epi[rr * 136 + c * 16 + (lane & 15)] = (ushort)bf16rne(acc[c][r]);
        }
    }
    __syncthreads();
    #pragma unroll
    for (int i = 0; i < 4; i++) {
        int id = tid + i * 512;
        int rr = id >> 4, q = id & 15;
        int grow = rowbase + rr;
        if (grow < nrows) {
            uint4 v = *(const uint4*)(epib + (rr >> 4) * 4352 + (rr & 15) * 272 + q * 16);
            ((uint4*)Y)[(size_t)grow * 16 + q] = v;
        }
    }
}

__global__ __launch_bounds__(512) void k_gemm_mfma(const unsigned* __restrict__ Xb,
                                                   const uint4* __restrict__ Bfr,
                                                   unsigned* __restrict__ Y, int nrows) {
    __shared__ uint4 bs[4096];                 // 64 KB
    int tid = threadIdx.x;
    int w = tid >> 6, lane = tid & 63;
    int rowbase = blockIdx.x * 128;
    #pragma unroll
    for (int i = 0; i < 8; i++) bs[tid + i * 512] = Bfr[tid + i * 512];
    int row = rowbase + w * 16 + (lane & 15);
    int rowc = min(row, nrows - 1);
    const uint4* X4 = (const uint4*)Xb;
    bfrag a[4];
    #pragma unroll
    for (int kk = 0; kk < 4; kk++) {
        uint4 av = X4[(size_t)rowc * 16 + kk * 4 + (lane >> 4)];
        a[kk] = *(const bfrag*)&av;
    }
    gemm_body(Bfr, Y, nrows, rowbase, a, bs);
}

// layer-1 variant: reads fp32 X, converts to bf16 fragments in-register.
__global__ __launch_bounds__(512) void k_gemm_mfma_f32(const float* __restrict__ X,
                                                       const uint4* __restrict__ Bfr,
                                                       unsigned* __restrict__ Y, int nrows) {
    __shared__ uint4 bs[4096];
    int tid = threadIdx.x;
    int w = tid >> 6, lane = tid & 63;
    int rowbase = blockIdx.x * 128;
    #pragma unroll
    for (int i = 0; i < 8; i++) bs[tid + i * 512] = Bfr[tid + i * 512];
    int row = rowbase + w * 16 + (lane & 15);
    int rowc = min(row, nrows - 1);
    const float4* X4 = (const float4*)X;
    bfrag a[4];
    #pragma unroll
    for (int kk = 0; kk < 4; kk++) {
        float4 f0 = X4[(size_t)rowc * 32 + kk * 8 + (lane >> 4) * 2];
        float4 f1 = X4[(size_t)rowc * 32 + kk * 8 + (lane >> 4) * 2 + 1];
        uint4 av = make_uint4(bf16rne(f0.x) | (bf16rne(f0.y) << 16),
                              bf16rne(f0.z) | (bf16rne(f0.w) << 16),
                              bf16rne(f1.x) | (bf16rne(f1.y) << 16),
                              bf16rne(f1.z) | (bf16rne(f1.w) << 16));
        a[kk] = *(const bfrag*)&av;
    }
    gemm_body(Bfr, Y, nrows, rowbase, a, bs);
}

// out[node](bf16) = relu(bn(segsum + bias)); one node per wave; fp32 accum.
__global__ __launch_bounds__(256) void k_aggregate(const unsigned* __restrict__ Hpre, const int* __restrict__ rowptr,
                                                   const int* __restrict__ csr_src,
                                                   const float* __restrict__ dinv,
                                                   const float* __restrict__ bias, const float* __restrict__ gamma,
                                                   const float* __restrict__ beta,
                                                   unsigned* __restrict__ out, int nnodes) {
    int lane = threadIdx.x & 63;
    int node = blockIdx.x * 4 + (threadIdx.x >> 6);
    if (node >= nnodes) return;
    float dn = dinv[node];
    unsigned hv = Hpre[(size_t)node * 64 + lane];
    float sl = dn * dn;
    float ax = __uint_as_float(hv << 16) * sl;
    float ay = __uint_as_float(hv & 0xffff0000u) * sl;
    int s = rowptr[node], e = rowptr[node + 1];
    int j = s;
    for (; j + 7 < e; j += 8) {
        int ss[8];
        #pragma unroll
        for (int q = 0; q < 8; q++) ss[q] = csr_src[j + q];
        float nn[8];
        #pragma unroll
        for (int q = 0; q < 8; q++) nn[q] = dinv[ss[q]] * dn;
        unsigned vv[8];
        #pragma unroll
        for (int q = 0; q < 8; q++) vv[q] = Hpre[(size_t)(unsigned)ss[q] * 64 + lane];
        #pragma unroll
        for (int q = 0; q < 8; q++) {
            ax = fmaf(__uint_as_float(vv[q] << 16), nn[q], ax);
            ay = fmaf(__uint_as_float(vv[q] & 0xffff0000u), nn[q], ay);
        }
    }
    for (; j < e; j++) {
        int s0 = csr_src[j];
        float n = dinv[s0] * dn;
        unsigned v = Hpre[(size_t)(unsigned)s0 * 64 + lane];
        ax = fmaf(__uint_as_float(v << 16), n, ax);
        ay = fmaf(__uint_as_float(v & 0xffff0000u), n, ay);
    }
    float2 bi = ((const float2*)bias)[lane];
    float2 ga = ((const float2*)gamma)[lane];
    float2 be = ((const float2*)beta)[lane];
    float vx = fmaf(ga.x * INV1P, ax + bi.x, be.x);
    float vy = fmaf(ga.y * INV1P, ay + bi.y, be.y);
    vx = fmaxf(vx, 0.f);
    vy = fmaxf(vy, 0.f);
    out[(size_t)node * 64 + lane] = bf16rne(vx) | (bf16rne(vy) << 16);
}

// pooled sums from bf16 H: 64 consecutive nodes per 64-thread block; batch sorted.
__global__ __launch_bounds__(64) void k_pool(const unsigned* __restrict__ Hf, const int* __restrict__ batch,
                                             float* __restrict__ pooled, float* __restrict__ cnt, int nnodes) {
    int t = threadIdx.x;
    int base = blockIdx.x * 64;
    if (base >= nnodes) return;
    int end = min(base + 64, nnodes);
    float ax = 0.f, ay = 0.f; int run = 0;
    int cur = batch[base];
    for (int i = base; i < end; i++) {
        int bg = batch[i];
        if (bg != cur) {
            atomicAdd(&pooled[(size_t)cur * 128 + 2 * t], ax);
            atomicAdd(&pooled[(size_t)cur * 128 + 2 * t + 1], ay);
            if (t == 0) atomicAdd(&cnt[cur], (float)run);
            ax = 0.f; ay = 0.f; run = 0; cur = bg;
        }
        unsigned u = Hf[(size_t)i * 64 + t];
        ax += __uint_as_float(u << 16);
        ay += __uint_as_float(u & 0xffff0000u);
        run++;
    }
    atomicAdd(&pooled[(size_t)cur * 128 + 2 * t], ax);
    atomicAdd(&pooled[(size_t)cur * 128 + 2 * t + 1], ay);
    if (t == 0) atomicAdd(&cnt[cur], (float)run);
}

// classifier: one 64-thread block per graph. 128 -> 64 (relu) -> 10
__global__ __launch_bounds__(64) void k_classifier(const float* __restrict__ pooled, const float* __restrict__ cnt,
                                                   const float* __restrict__ Wc1, const float* __restrict__ bc1,
                                                   const float* __restrict__ Wc2, const float* __restrict__ bc2,
                                                   float* __restrict__ outp, int ngraphs) {
    __shared__ float p[128];
    __shared__ float z[64];
    int g = blockIdx.x;
    int tid = threadIdx.x;
    float inv = 1.0f / fmaxf(cnt[g], 1.0f);
    p[tid]      = pooled[(size_t)g * 128 + tid] * inv;
    p[tid + 64] = pooled[(size_t)g * 128 + 64 + tid] * inv;
    __syncthreads();
    float a = bc1[tid];
    #pragma unroll 8
    for (int k = 0; k < 128; k++) a += p[k] * Wc1[k * 64 + tid];
    z[tid] = fmaxf(a, 0.f);
    __syncthreads();
    if (tid < 10) {
        float o = bc2[tid];
        #pragma unroll 8
        for (int j = 0; j < 64; j++) o += z[j] * Wc2[j * 10 + tid];
        outp[(size_t)g * 10 + tid] = o;
    }
}

// ---------------- launch ----------------

static inline size_t align16(size_t v) { return (v + 15) & ~(size_t)15; }

extern "C" void kernel_launch(void* const* d_in, const int* in_sizes, int n_in,
                              void* d_out, int out_size, void* d_ws, size_t ws_size,
                              hipStream_t stream) {
    const float* x      = (const float*)d_in[0];
    const int*   ei     = (const int*)d_in[1];
    const int*   batch  = (const int*)d_in[2];
    const float* W1 = (const float*)d_in[3];  const float* b1 = (const float*)d_in[4];
    const float* W2 = (const float*)d_in[5];  const float* b2 = (const float*)d_in[6];
    const float* W3 = (const float*)d_in[7];  const float* b3 = (const float*)d_in[8];
    const float* g1 = (const float*)d_in[9];  const float* be1 = (const float*)d_in[10];
    const float* g2 = (const float*)d_in[11]; const float* be2 = (const float*)d_in[12];
    const float* g3 = (const float*)d_in[13]; const float* be3 = (const float*)d_in[14];
    const float* Wc1 = (const float*)d_in[15]; const float* bc1 = (const float*)d_in[16];
    const float* Wc2 = (const float*)d_in[17]; const float* bc2 = (const float*)d_in[18];

    const int N = in_sizes[0] / 128;
    const int E = in_sizes[1] / 2;
    const int G = out_size / 10;
    const int* srcp = ei;
    const int* dstp = ei + E;
    const int NB = (N + 511) >> 9;   // dst buckets of 512 nodes

    // workspace layout (16B-aligned slots)
    char* ws = (char*)d_ws;
    size_t off = 0;
    unsigned* bufA = (unsigned*)(ws + off); off = align16(off + (size_t)N * 64 * 4);
    unsigned* bufB = (unsigned*)(ws + off); off = align16(off + (size_t)N * 64 * 4);
    uint4* Bfr1 = (uint4*)(ws + off); off = align16(off + 4096 * 16);
    uint4* Bfr2 = (uint4*)(ws + off); off = align16(off + 4096 * 16);
    uint4* Bfr3 = (uint4*)(ws + off); off = align16(off + 4096 * 16);
    int*   csr_src = (int*)(ws + off);  off = align16(off + (size_t)E * 4);
    unsigned* binned = (unsigned*)(ws + off); off = align16(off + (size_t)E * 4);
    int*   deg    = (int*)(ws + off);   off = align16(off + (size_t)N * 4);
    float* dinv   = (float*)(ws + off); off = align16(off + (size_t)N * 4);
    int*   rowptr = (int*)(ws + off);   off = align16(off + (size_t)(N + 1) * 4);
    int*   gcursor = (int*)(ws + off);  off = align16(off + 256 * 4);
    float* pooled = (float*)(ws + off); off = align16(off + (size_t)G * 128 * 4);
    float* cnt    = (float*)(ws + off); off = align16(off + (size_t)G * 4);
    int*   bsums  = (int*)(ws + off);   off = align16(off + 256 * 4);
    (void)ws_size;

    int gN  = (N + 255) / 256;
    int gE  = (E + 255) / 256;
    int nb  = (N + 1023) / 1024;

    // weight prep (independent of graph structure)
    k_prepw<<<8, 256, 0, stream>>>(W1, Bfr1);
    k_prepw<<<8, 256, 0, stream>>>(W2, Bfr2);
    k_prepw<<<8, 256, 0, stream>>>(W3, Bfr3);

    // graph structure
    k_init_deg<<<gN, 256, 0, stream>>>(deg, N);
    k_count<<<gE, 256, 0, stream>>>(dstp, deg, E);
    k_dinv<<<gN, 256, 0, stream>>>(deg, dinv, N);
    k_scan1<<<nb, 256, 0, stream>>>(deg, rowptr, bsums, N);
    k_scan2<<<1, 128, 0, stream>>>(bsums, nb);
    k_scan3<<<gN, 256, 0, stream>>>(rowptr, bsums, N, E);
    k_initcur<<<1, 256, 0, stream>>>(rowptr, gcursor, NB);
    k_binA<<<(E + 8191) / 8192, 256, 0, stream>>>(srcp, dstp, gcursor, binned, E);
    k_binB<<<NB, 256, 0, stream>>>(binned, rowptr, csr_src, N);

    int gGemm = (N + 127) / 128;
    int gAgg  = (N + 3) / 4;

    // layer 1 (fp32 input, in-register convert)
    k_gemm_mfma_f32<<<gGemm, 512, 0, stream>>>(x, Bfr1, bufA, N);
    k_aggregate<<<gAgg, 256, 0, stream>>>(bufA, rowptr, csr_src, dinv, b1, g1, be1, bufB, N);
    // layer 2
    k_gemm_mfma<<<gGemm, 512, 0, stream>>>(bufB, Bfr2, bufA, N);
    k_aggregate<<<gAgg, 256, 0, stream>>>(bufA, rowptr, csr_src, dinv, b2, g2, be2, bufB, N);
    // layer 3
    k_gemm_mfma<<<gGemm, 512, 0, stream>>>(bufB, Bfr3, bufA, N);
    k_aggregate<<<gAgg, 256, 0, stream>>>(bufA, rowptr, csr_src, dinv, b3, g3, be3, bufB, N);

    // pooling
    hipMemsetAsync(pooled, 0, ((size_t)G * 128 + G) * 4, stream);
    int gPool = (N + 63) / 64;
    k_pool<<<gPool, 64, 0, stream>>>(bufB, batch, pooled, cnt, N);

    // classifier
    k_classifier<<<G, 64, 0, stream>>>(pooled, cnt, Wc1, bc1, Wc2, bc2, (float*)d_out, G);
}

// Round 6
// 388.579 us; speedup vs baseline: 3.0206x; 1.1244x over previous
//
#include <hip/hip_runtime.h>
#include <hip/hip_bf16.h>

#define INV1P 0.9999950000374997f

typedef __attribute__((ext_vector_type(8))) short bfrag;   // 8 x bf16 (4 VGPR)
typedef __attribute__((ext_vector_type(4))) float f32x4;   // MFMA accumulator

static __device__ __forceinline__ unsigned bf16rne(float f) {
    unsigned u = __float_as_uint(f);
    return (u + 0x7fffu + ((u >> 16) & 1u)) >> 16;
}
static __device__ __forceinline__ float bflo(unsigned u) { return __uint_as_float(u << 16); }
static __device__ __forceinline__ float bfhi(unsigned u) { return __uint_as_float(u & 0xffff0000u); }

// ---------------- graph-structure kernels ----------------

__global__ __launch_bounds__(256) void k_init_deg(int* __restrict__ deg, int n) {
    int i = blockIdx.x * 256 + threadIdx.x;
    if (i < n) deg[i] = 1;  // self-loop
}

__global__ __launch_bounds__(256) void k_count(const int* __restrict__ dst, int* __restrict__ deg, int e) {
    int i = blockIdx.x * 256 + threadIdx.x;
    if (i < e) atomicAdd(&deg[dst[i]], 1);
}

__global__ __launch_bounds__(256) void k_dinv(const int* __restrict__ deg, float* __restrict__ dinv, int n) {
    int i = blockIdx.x * 256 + threadIdx.x;
    if (i < n) dinv[i] = rsqrtf((float)deg[i]);
}

// exclusive scan of (deg[i]-1) -> rowptr, in 3 stages. items/block = 1024.
__global__ __launch_bounds__(256) void k_scan1(const int* __restrict__ deg, int* __restrict__ part,
                                               int* __restrict__ bsums, int n) {
    __shared__ int sh[256];
    int tid = threadIdx.x;
    int base = blockIdx.x * 1024 + tid * 4;
    int v[4]; int s = 0;
    #pragma unroll
    for (int j = 0; j < 4; j++) {
        v[j] = (base + j < n) ? (deg[base + j] - 1) : 0;
        s += v[j];
    }
    sh[tid] = s; __syncthreads();
    for (int off = 1; off < 256; off <<= 1) {
        int t2 = (tid >= off) ? sh[tid - off] : 0;
        __syncthreads();
        sh[tid] += t2;
        __syncthreads();
    }
    int incl = sh[tid];
    int run = incl - s;
    #pragma unroll
    for (int j = 0; j < 4; j++) {
        if (base + j < n) part[base + j] = run;
        run += v[j];
    }
    if (tid == 255) bsums[blockIdx.x] = incl;
}

__global__ __launch_bounds__(128) void k_scan2(int* __restrict__ bsums, int nb) {
    __shared__ int sh[128];
    int tid = threadIdx.x;
    int v = (tid < nb) ? bsums[tid] : 0;
    sh[tid] = v; __syncthreads();
    for (int off = 1; off < 128; off <<= 1) {
        int t2 = (tid >= off) ? sh[tid - off] : 0;
        __syncthreads();
        sh[tid] += t2;
        __syncthreads();
    }
    if (tid < nb) bsums[tid] = sh[tid] - v;
}

__global__ __launch_bounds__(256) void k_scan3(int* __restrict__ rowptr, const int* __restrict__ bsums,
                                               int n, int totalE) {
    int i = blockIdx.x * 256 + threadIdx.x;
    if (i < n) rowptr[i] = rowptr[i] + bsums[i >> 10];
    if (i == 0) rowptr[n] = totalE;
}

// gcursor[b] = rowptr[512*b]  (bucket b covers nodes [512b, 512b+512))
__global__ __launch_bounds__(256) void k_initcur(const int* __restrict__ rowptr, int* __restrict__ gcursor, int nbuckets) {
    int b = threadIdx.x + blockIdx.x * 256;
    if (b < nbuckets) gcursor[b] = rowptr[b << 9];
}

// pass A: bin edges by dst-bucket. 8192 edges/block, packed (src | dst_low<<17).
__global__ __launch_bounds__(256) void k_binA(const int* __restrict__ src, const int* __restrict__ dst,
                                              int* __restrict__ gcursor, unsigned* __restrict__ binned, int e) {
    __shared__ unsigned pk[8192];
    __shared__ unsigned char bk[8192];
    __shared__ int hist[256];
    __shared__ int base[256];
    int tid = threadIdx.x;
    hist[tid] = 0;
    __syncthreads();
    int cbase = blockIdx.x * 8192;
    int cnt = min(8192, e - cbase);
    for (int j = tid; j < cnt; j += 256) {
        int s = src[cbase + j], d = dst[cbase + j];
        unsigned b = (unsigned)d >> 9;
        pk[j] = (unsigned)s | (((unsigned)d & 511u) << 17);
        bk[j] = (unsigned char)b;
        atomicAdd(&hist[b], 1);
    }
    __syncthreads();
    int h = hist[tid];
    base[tid] = (h > 0) ? atomicAdd(&gcursor[tid], h) : 0;
    hist[tid] = 0;
    __syncthreads();
    for (int j = tid; j < cnt; j += 256) {
        unsigned b = bk[j];
        int off = atomicAdd(&hist[b], 1);
        binned[base[b] + off] = pk[j];
    }
}

// pass B: one block per bucket; scatter binned entries into dense CSR order.
__global__ __launch_bounds__(256) void k_binB(const unsigned* __restrict__ binned, const int* __restrict__ rowptr,
                                              int* __restrict__ csr_src, int n) {
    __shared__ int rp[513];
    __shared__ int cur[512];
    int b = blockIdx.x, tid = threadIdx.x;
    int nstart = b << 9;
    int nend = min(nstart + 512, n);
    int nn = nend - nstart;
    for (int j = tid; j < nn + 1; j += 256) rp[j] = rowptr[nstart + j];
    for (int j = tid; j < nn; j += 256) cur[j] = 0;
    __syncthreads();
    int s0 = rp[0], s1 = rp[nn];
    for (int j = s0 + tid; j < s1; j += 256) {
        unsigned p = binned[j];
        int nl = (p >> 17) & 511;
        int sv = p & 0x1ffff;
        int idx = atomicAdd(&cur[nl], 1);
        csr_src[rp[nl] + idx] = sv;
    }
}

// ---------------- dense kernels ----------------

// Build MFMA B-operand fragments from fp32 W[128][128] (row-major, W[k][n]).
// part 0 = bf16_hi(W), part 1 = bf16(W - hi)  (split for accuracy).
__global__ __launch_bounds__(256) void k_prepw(const float* __restrict__ W, uint4* __restrict__ Bf) {
    int id = blockIdx.x * 256 + threadIdx.x;   // 0..2047
    int lane = id & 63;
    int e = id >> 6;                            // 0..31
    int kk = e >> 3, c = e & 7;
    int kbase = kk * 32 + (lane >> 4) * 8;
    int col = c * 16 + (lane & 15);
    unsigned hi[8], lo[8];
    #pragma unroll
    for (int j = 0; j < 8; j++) {
        float w = W[(kbase + j) * 128 + col];
        unsigned h = bf16rne(w);
        float rh = __uint_as_float(h << 16);
        unsigned l = bf16rne(w - rh);
        hi[j] = h; lo[j] = l;
    }
    uint4 H = make_uint4(hi[0] | (hi[1] << 16), hi[2] | (hi[3] << 16),
                         hi[4] | (hi[5] << 16), hi[6] | (hi[7] << 16));
    uint4 L = make_uint4(lo[0] | (lo[1] << 16), lo[2] | (lo[3] << 16),
                         lo[4] | (lo[5] << 16), lo[6] | (lo[7] << 16));
    Bf[e * 64 + lane] = H;
    Bf[2048 + e * 64 + lane] = L;
}

// common MFMA GEMM body: a[4] fragments already loaded.
// Y[n,128](bf16) = A @ (Whi+Wlo). 512 threads = 8 waves, 128 rows/block.
static __device__ __forceinline__ void gemm_body(const uint4* __restrict__ Bfr, unsigned* __restrict__ Y,
                                                 int nrows, int rowbase, bfrag* a, uint4* bs) {
    int tid = threadIdx.x;
    int w = tid >> 6, lane = tid & 63;
    __syncthreads();   // bs staged
    f32x4 acc[8];
    #pragma unroll
    for (int c = 0; c < 8; c++) acc[c] = (f32x4){0.f, 0.f, 0.f, 0.f};
    #pragma unroll
    for (int kk = 0; kk < 4; kk++) {
        #pragma unroll
        for (int c = 0; c < 8; c++) {
            bfrag bh = *(const bfrag*)&bs[(kk * 8 + c) * 64 + lane];
            bfrag bl = *(const bfrag*)&bs[2048 + (kk * 8 + c) * 64 + lane];
            acc[c] = __builtin_amdgcn_mfma_f32_16x16x32_bf16(a[kk], bh, acc[c], 0, 0, 0);
            acc[c] = __builtin_amdgcn_mfma_f32_16x16x32_bf16(a[kk], bl, acc[c], 0, 0, 0);
        }
    }
    // epilogue: bounce through LDS (per-wave 16 x 136 ushorts) -> coalesced stores
    __syncthreads();
    char* epib = (char*)bs;
    ushort* epi = (ushort*)(epib + w * 4352);
    #pragma unroll
    for (int c = 0; c < 8; c++) {
        #pragma unroll
        for (int r = 0; r < 4; r++) {
            int rr = (lane >> 4) * 4 + r;
            epi[rr * 136 + c * 16 + (lane & 15)] = (ushort)bf16rne(acc[c][r]);
        }
    }
    __syncthreads();
    #pragma unroll
    for (int i = 0; i < 4; i++) {
        int id = tid + i * 512;
        int rr = id >> 4, q = id & 15;
        int grow = rowbase + rr;
        if (grow < nrows) {
            uint4 v = *(const uint4*)(epib + (rr >> 4) * 4352 + (rr & 15) * 272 + q * 16);
            ((uint4*)Y)[(size_t)grow * 16 + q] = v;
        }
    }
}

__global__ __launch_bounds__(512) void k_gemm_mfma(const unsigned* __restrict__ Xb,
                                                   const uint4* __restrict__ Bfr,
                                                   unsigned* __restrict__ Y, int nrows) {
    __shared__ uint4 bs[4096];                 // 64 KB
    int tid = threadIdx.x;
    int w = tid >> 6, lane = tid & 63;
    int rowbase = blockIdx.x * 128;
    #pragma unroll
    for (int i = 0; i < 8; i++) bs[tid + i * 512] = Bfr[tid + i * 512];
    int row = rowbase + w * 16 + (lane & 15);
    int rowc = min(row, nrows - 1);
    const uint4* X4 = (const uint4*)Xb;
    bfrag a[4];
    #pragma unroll
    for (int kk = 0; kk < 4; kk++) {
        uint4 av = X4[(size_t)rowc * 16 + kk * 4 + (lane >> 4)];
        a[kk] = *(const bfrag*)&av;
    }
    gemm_body(Bfr, Y, nrows, rowbase, a, bs);
}

// layer-1 variant: reads fp32 X, converts to bf16 fragments in-register.
__global__ __launch_bounds__(512) void k_gemm_mfma_f32(const float* __restrict__ X,
                                                       const uint4* __restrict__ Bfr,
                                                       unsigned* __restrict__ Y, int nrows) {
    __shared__ uint4 bs[4096];
    int tid = threadIdx.x;
    int w = tid >> 6, lane = tid & 63;
    int rowbase = blockIdx.x * 128;
    #pragma unroll
    for (int i = 0; i < 8; i++) bs[tid + i * 512] = Bfr[tid + i * 512];
    int row = rowbase + w * 16 + (lane & 15);
    int rowc = min(row, nrows - 1);
    const float4* X4 = (const float4*)X;
    bfrag a[4];
    #pragma unroll
    for (int kk = 0; kk < 4; kk++) {
        float4 f0 = X4[(size_t)rowc * 32 + kk * 8 + (lane >> 4) * 2];
        float4 f1 = X4[(size_t)rowc * 32 + kk * 8 + (lane >> 4) * 2 + 1];
        uint4 av = make_uint4(bf16rne(f0.x) | (bf16rne(f0.y) << 16),
                              bf16rne(f0.z) | (bf16rne(f0.w) << 16),
                              bf16rne(f1.x) | (bf16rne(f1.y) << 16),
                              bf16rne(f1.z) | (bf16rne(f1.w) << 16));
        a[kk] = *(const bfrag*)&av;
    }
    gemm_body(Bfr, Y, nrows, rowbase, a, bs);
}

// out[node](bf16) = relu(bn(segsum + bias)); 16 lanes per node, uint4/lane.
// 4 independent nodes per wave -> 4x gather MLP per load instruction.
__global__ __launch_bounds__(256) void k_aggregate(const uint4* __restrict__ H4, const int* __restrict__ rowptr,
                                                   const int* __restrict__ csr_src,
                                                   const float* __restrict__ dinv,
                                                   const float* __restrict__ bias, const float* __restrict__ gamma,
                                                   const float* __restrict__ beta,
                                                   uint4* __restrict__ out4, int nnodes) {
    int tid = blockIdx.x * 256 + threadIdx.x;
    int node = tid >> 4;
    int l = tid & 15;                    // cols 8l .. 8l+7
    if (node >= nnodes) return;
    float dn = dinv[node];
    float sl = dn * dn;
    float acc[8];
    {
        uint4 hv = H4[(size_t)node * 16 + l];
        acc[0] = bflo(hv.x) * sl; acc[1] = bfhi(hv.x) * sl;
        acc[2] = bflo(hv.y) * sl; acc[3] = bfhi(hv.y) * sl;
        acc[4] = bflo(hv.z) * sl; acc[5] = bfhi(hv.z) * sl;
        acc[6] = bflo(hv.w) * sl; acc[7] = bfhi(hv.w) * sl;
    }
    int s = rowptr[node], e = rowptr[node + 1];
    int j = s;
    for (; j + 3 < e; j += 4) {
        int s0 = csr_src[j], s1 = csr_src[j + 1], s2 = csr_src[j + 2], s3 = csr_src[j + 3];
        uint4 v0 = H4[(size_t)s0 * 16 + l];
        uint4 v1 = H4[(size_t)s1 * 16 + l];
        uint4 v2 = H4[(size_t)s2 * 16 + l];
        uint4 v3 = H4[(size_t)s3 * 16 + l];
        float n0 = dinv[s0] * dn, n1 = dinv[s1] * dn, n2 = dinv[s2] * dn, n3 = dinv[s3] * dn;
        acc[0] = fmaf(bflo(v0.x), n0, acc[0]); acc[1] = fmaf(bfhi(v0.x), n0, acc[1]);
        acc[2] = fmaf(bflo(v0.y), n0, acc[2]); acc[3] = fmaf(bfhi(v0.y), n0, acc[3]);
        acc[4] = fmaf(bflo(v0.z), n0, acc[4]); acc[5] = fmaf(bfhi(v0.z), n0, acc[5]);
        acc[6] = fmaf(bflo(v0.w), n0, acc[6]); acc[7] = fmaf(bfhi(v0.w), n0, acc[7]);
        acc[0] = fmaf(bflo(v1.x), n1, acc[0]); acc[1] = fmaf(bfhi(v1.x), n1, acc[1]);
        acc[2] = fmaf(bflo(v1.y), n1, acc[2]); acc[3] = fmaf(bfhi(v1.y), n1, acc[3]);
        acc[4] = fmaf(bflo(v1.z), n1, acc[4]); acc[5] = fmaf(bfhi(v1.z), n1, acc[5]);
        acc[6] = fmaf(bflo(v1.w), n1, acc[6]); acc[7] = fmaf(bfhi(v1.w), n1, acc[7]);
        acc[0] = fmaf(bflo(v2.x), n2, acc[0]); acc[1] = fmaf(bfhi(v2.x), n2, acc[1]);
        acc[2] = fmaf(bflo(v2.y), n2, acc[2]); acc[3] = fmaf(bfhi(v2.y), n2, acc[3]);
        acc[4] = fmaf(bflo(v2.z), n2, acc[4]); acc[5] = fmaf(bfhi(v2.z), n2, acc[5]);
        acc[6] = fmaf(bflo(v2.w), n2, acc[6]); acc[7] = fmaf(bfhi(v2.w), n2, acc[7]);
        acc[0] = fmaf(bflo(v3.x), n3, acc[0]); acc[1] = fmaf(bfhi(v3.x), n3, acc[1]);
        acc[2] = fmaf(bflo(v3.y), n3, acc[2]); acc[3] = fmaf(bfhi(v3.y), n3, acc[3]);
        acc[4] = fmaf(bflo(v3.z), n3, acc[4]); acc[5] = fmaf(bfhi(v3.z), n3, acc[5]);
        acc[6] = fmaf(bflo(v3.w), n3, acc[6]); acc[7] = fmaf(bfhi(v3.w), n3, acc[7]);
    }
    for (; j < e; j++) {
        int s0 = csr_src[j];
        uint4 v0 = H4[(size_t)s0 * 16 + l];
        float n0 = dinv[s0] * dn;
        acc[0] = fmaf(bflo(v0.x), n0, acc[0]); acc[1] = fmaf(bfhi(v0.x), n0, acc[1]);
        acc[2] = fmaf(bflo(v0.y), n0, acc[2]); acc[3] = fmaf(bfhi(v0.y), n0, acc[3]);
        acc[4] = fmaf(bflo(v0.z), n0, acc[4]); acc[5] = fmaf(bfhi(v0.z), n0, acc[5]);
        acc[6] = fmaf(bflo(v0.w), n0, acc[6]); acc[7] = fmaf(bfhi(v0.w), n0, acc[7]);
    }
    float4 bi0 = ((const float4*)bias)[l * 2],  bi1 = ((const float4*)bias)[l * 2 + 1];
    float4 ga0 = ((const float4*)gamma)[l * 2], ga1 = ((const float4*)gamma)[l * 2 + 1];
    float4 be0 = ((const float4*)beta)[l * 2],  be1 = ((const float4*)beta)[l * 2 + 1];
    float r[8];
    r[0] = fmaxf(fmaf(ga0.x * INV1P, acc[0] + bi0.x, be0.x), 0.f);
    r[1] = fmaxf(fmaf(ga0.y * INV1P, acc[1] + bi0.y, be0.y), 0.f);
    r[2] = fmaxf(fmaf(ga0.z * INV1P, acc[2] + bi0.z, be0.z), 0.f);
    r[3] = fmaxf(fmaf(ga0.w * INV1P, acc[3] + bi0.w, be0.w), 0.f);
    r[4] = fmaxf(fmaf(ga1.x * INV1P, acc[4] + bi1.x, be1.x), 0.f);
    r[5] = fmaxf(fmaf(ga1.y * INV1P, acc[5] + bi1.y, be1.y), 0.f);
    r[6] = fmaxf(fmaf(ga1.z * INV1P, acc[6] + bi1.z, be1.z), 0.f);
    r[7] = fmaxf(fmaf(ga1.w * INV1P, acc[7] + bi1.w, be1.w), 0.f);
    uint4 o;
    o.x = bf16rne(r[0]) | (bf16rne(r[1]) << 16);
    o.y = bf16rne(r[2]) | (bf16rne(r[3]) << 16);
    o.z = bf16rne(r[4]) | (bf16rne(r[5]) << 16);
    o.w = bf16rne(r[6]) | (bf16rne(r[7]) << 16);
    out4[(size_t)node * 16 + l] = o;
}

// pooled sums from bf16 H: 64 consecutive nodes per 64-thread block; batch sorted.
__global__ __launch_bounds__(64) void k_pool(const unsigned* __restrict__ Hf, const int* __restrict__ batch,
                                             float* __restrict__ pooled, float* __restrict__ cnt, int nnodes) {
    int t = threadIdx.x;
    int base = blockIdx.x * 64;
    if (base >= nnodes) return;
    int end = min(base + 64, nnodes);
    float ax = 0.f, ay = 0.f; int run = 0;
    int cur = batch[base];
    for (int i = base; i < end; i++) {
        int bg = batch[i];
        if (bg != cur) {
            atomicAdd(&pooled[(size_t)cur * 128 + 2 * t], ax);
            atomicAdd(&pooled[(size_t)cur * 128 + 2 * t + 1], ay);
            if (t == 0) atomicAdd(&cnt[cur], (float)run);
            ax = 0.f; ay = 0.f; run = 0; cur = bg;
        }
        unsigned u = Hf[(size_t)i * 64 + t];
        ax += bflo(u);
        ay += bfhi(u);
        run++;
    }
    atomicAdd(&pooled[(size_t)cur * 128 + 2 * t], ax);
    atomicAdd(&pooled[(size_t)cur * 128 + 2 * t + 1], ay);
    if (t == 0) atomicAdd(&cnt[cur], (float)run);
}

// classifier: one 64-thread block per graph. 128 -> 64 (relu) -> 10
__global__ __launch_bounds__(64) void k_classifier(const float* __restrict__ pooled, const float* __restrict__ cnt,
                                                   const float* __restrict__ Wc1, const float* __restrict__ bc1,
                                                   const float* __restrict__ Wc2, const float* __restrict__ bc2,
                                                   float* __restrict__ outp, int ngraphs) {
    __shared__ float p[128];
    __shared__ float z[64];
    int g = blockIdx.x;
    int tid = threadIdx.x;
    float inv = 1.0f / fmaxf(cnt[g], 1.0f);
    p[tid]      = pooled[(size_t)g * 128 + tid] * inv;
    p[tid + 64] = pooled[(size_t)g * 128 + 64 + tid] * inv;
    __syncthreads();
    float a = bc1[tid];
    #pragma unroll 8
    for (int k = 0; k < 128; k++) a += p[k] * Wc1[k * 64 + tid];
    z[tid] = fmaxf(a, 0.f);
    __syncthreads();
    if (tid < 10) {
        float o = bc2[tid];
        #pragma unroll 8
        for (int j = 0; j < 64; j++) o += z[j] * Wc2[j * 10 + tid];
        outp[(size_t)g * 10 + tid] = o;
    }
}

// ---------------- launch ----------------

static inline size_t align16(size_t v) { return (v + 15) & ~(size_t)15; }

extern "C" void kernel_launch(void* const* d_in, const int* in_sizes, int n_in,
                              void* d_out, int out_size, void* d_ws, size_t ws_size,
                              hipStream_t stream) {
    const float* x      = (const float*)d_in[0];
    const int*   ei     = (const int*)d_in[1];
    const int*   batch  = (const int*)d_in[2];
    const float* W1 = (const float*)d_in[3];  const float* b1 = (const float*)d_in[4];
    const float* W2 = (const float*)d_in[5];  const float* b2 = (const float*)d_in[6];
    const float* W3 = (const float*)d_in[7];  const float* b3 = (const float*)d_in[8];
    const float* g1 = (const float*)d_in[9];  const float* be1 = (const float*)d_in[10];
    const float* g2 = (const float*)d_in[11]; const float* be2 = (const float*)d_in[12];
    const float* g3 = (const float*)d_in[13]; const float* be3 = (const float*)d_in[14];
    const float* Wc1 = (const float*)d_in[15]; const float* bc1 = (const float*)d_in[16];
    const float* Wc2 = (const float*)d_in[17]; const float* bc2 = (const float*)d_in[18];

    const int N = in_sizes[0] / 128;
    const int E = in_sizes[1] / 2;
    const int G = out_size / 10;
    const int* srcp = ei;
    const int* dstp = ei + E;
    const int NB = (N + 511) >> 9;   // dst buckets of 512 nodes

    // workspace layout (16B-aligned slots)
    char* ws = (char*)d_ws;
    size_t off = 0;
    unsigned* bufA = (unsigned*)(ws + off); off = align16(off + (size_t)N * 64 * 4);
    unsigned* bufB = (unsigned*)(ws + off); off = align16(off + (size_t)N * 64 * 4);
    uint4* Bfr1 = (uint4*)(ws + off); off = align16(off + 4096 * 16);
    uint4* Bfr2 = (uint4*)(ws + off); off = align16(off + 4096 * 16);
    uint4* Bfr3 = (uint4*)(ws + off); off = align16(off + 4096 * 16);
    int*   csr_src = (int*)(ws + off);  off = align16(off + (size_t)E * 4);
    unsigned* binned = (unsigned*)(ws + off); off = align16(off + (size_t)E * 4);
    int*   deg    = (int*)(ws + off);   off = align16(off + (size_t)N * 4);
    float* dinv   = (float*)(ws + off); off = align16(off + (size_t)N * 4);
    int*   rowptr = (int*)(ws + off);   off = align16(off + (size_t)(N + 1) * 4);
    int*   gcursor = (int*)(ws + off);  off = align16(off + 256 * 4);
    float* pooled = (float*)(ws + off); off = align16(off + (size_t)G * 128 * 4);
    float* cnt    = (float*)(ws + off); off = align16(off + (size_t)G * 4);
    int*   bsums  = (int*)(ws + off);   off = align16(off + 256 * 4);
    (void)ws_size;

    int gN  = (N + 255) / 256;
    int gE  = (E + 255) / 256;
    int nb  = (N + 1023) / 1024;

    // weight prep (independent of graph structure)
    k_prepw<<<8, 256, 0, stream>>>(W1, Bfr1);
    k_prepw<<<8, 256, 0, stream>>>(W2, Bfr2);
    k_prepw<<<8, 256, 0, stream>>>(W3, Bfr3);

    // graph structure
    k_init_deg<<<gN, 256, 0, stream>>>(deg, N);
    k_count<<<gE, 256, 0, stream>>>(dstp, deg, E);
    k_dinv<<<gN, 256, 0, stream>>>(deg, dinv, N);
    k_scan1<<<nb, 256, 0, stream>>>(deg, rowptr, bsums, N);
    k_scan2<<<1, 128, 0, stream>>>(bsums, nb);
    k_scan3<<<gN, 256, 0, stream>>>(rowptr, bsums, N, E);
    k_initcur<<<1, 256, 0, stream>>>(rowptr, gcursor, NB);
    k_binA<<<(E + 8191) / 8192, 256, 0, stream>>>(srcp, dstp, gcursor, binned, E);
    k_binB<<<NB, 256, 0, stream>>>(binned, rowptr, csr_src, N);

    int gGemm = (N + 127) / 128;
    int gAgg  = (N * 16 + 255) / 256;

    // layer 1 (fp32 input, in-register convert)
    k_gemm_mfma_f32<<<gGemm, 512, 0, stream>>>(x, Bfr1, bufA, N);
    k_aggregate<<<gAgg, 256, 0, stream>>>((const uint4*)bufA, rowptr, csr_src, dinv, b1, g1, be1, (uint4*)bufB, N);
    // layer 2
    k_gemm_mfma<<<gGemm, 512, 0, stream>>>(bufB, Bfr2, bufA, N);
    k_aggregate<<<gAgg, 256, 0, stream>>>((const uint4*)bufA, rowptr, csr_src, dinv, b2, g2, be2, (uint4*)bufB, N);
    // layer 3
    k_gemm_mfma<<<gGemm, 512, 0, stream>>>(bufB, Bfr3, bufA, N);
    k_aggregate<<<gAgg, 256, 0, stream>>>((const uint4*)bufA, rowptr, csr_src, dinv, b3, g3, be3, (uint4*)bufB, N);

    // pooling
    hipMemsetAsync(pooled, 0, ((size_t)G * 128 + G) * 4, stream);
    int gPool = (N + 63) / 64;
    k_pool<<<gPool, 64, 0, stream>>>(bufB, batch, pooled, cnt, N);

    // classifier
    k_classifier<<<G, 64, 0, stream>>>(pooled, cnt, Wc1, bc1, Wc2, bc2, (float*)d_out, G);
}

// Round 7
// 334.025 us; speedup vs baseline: 3.5140x; 1.1633x over previous
//
#include <hip/hip_runtime.h>
#include <hip/hip_bf16.h>

#define INV1P 0.9999950000374997f

typedef __attribute__((ext_vector_type(8))) short bfrag;   // 8 x bf16 (4 VGPR)
typedef __attribute__((ext_vector_type(4))) float f32x4;   // MFMA accumulator

static __device__ __forceinline__ unsigned bf16rne(float f) {
    unsigned u = __float_as_uint(f);
    return (u + 0x7fffu + ((u >> 16) & 1u)) >> 16;
}
static __device__ __forceinline__ float bflo(unsigned u) { return __uint_as_float(u << 16); }
static __device__ __forceinline__ float bfhi(unsigned u) { return __uint_as_float(u & 0xffff0000u); }

// ---------------- graph-structure kernels (atomic-free CSR build) ----------------

// per-block LDS histogram of dst-buckets -> global bucket counts (256 targets only)
__global__ __launch_bounds__(256) void k_bcount(const int* __restrict__ dst, int* __restrict__ bucket_cnt, int e) {
    __shared__ int hist[256];
    int tid = threadIdx.x;
    hist[tid] = 0;
    __syncthreads();
    int base = blockIdx.x * 8192;
    int cnt = min(8192, e - base);
    for (int j = tid; j < cnt; j += 256)
        atomicAdd(&hist[(unsigned)dst[base + j] >> 9], 1);
    __syncthreads();
    int h = hist[tid];
    if (h) atomicAdd(&bucket_cnt[tid], h);
}

// 1-block exclusive scan of 256 bucket counts -> bucket_base[257], gcursor copy
__global__ __launch_bounds__(256) void k_bscan(const int* __restrict__ bucket_cnt, int* __restrict__ bucket_base,
                                               int* __restrict__ gcursor, int etot) {
    __shared__ int sh[256];
    int tid = threadIdx.x;
    int v = bucket_cnt[tid];
    sh[tid] = v; __syncthreads();
    for (int off = 1; off < 256; off <<= 1) {
        int t2 = (tid >= off) ? sh[tid - off] : 0;
        __syncthreads();
        sh[tid] += t2;
        __syncthreads();
    }
    int excl = sh[tid] - v;
    bucket_base[tid] = excl;
    gcursor[tid] = excl;
    if (tid == 255) bucket_base[256] = etot;
}

// pass A: bin edges by dst-bucket. 8192 edges/block, packed (src | dst_low<<17).
__global__ __launch_bounds__(256) void k_binA(const int* __restrict__ src, const int* __restrict__ dst,
                                              int* __restrict__ gcursor, unsigned* __restrict__ binned, int e) {
    __shared__ unsigned pk[8192];
    __shared__ unsigned char bk[8192];
    __shared__ int hist[256];
    __shared__ int base[256];
    int tid = threadIdx.x;
    hist[tid] = 0;
    __syncthreads();
    int cbase = blockIdx.x * 8192;
    int cnt = min(8192, e - cbase);
    for (int j = tid; j < cnt; j += 256) {
        int s = src[cbase + j], d = dst[cbase + j];
        unsigned b = (unsigned)d >> 9;
        pk[j] = (unsigned)s | (((unsigned)d & 511u) << 17);
        bk[j] = (unsigned char)b;
        atomicAdd(&hist[b], 1);
    }
    __syncthreads();
    int h = hist[tid];
    base[tid] = (h > 0) ? atomicAdd(&gcursor[tid], h) : 0;
    hist[tid] = 0;
    __syncthreads();
    for (int j = tid; j < cnt; j += 256) {
        unsigned b = bk[j];
        int off = atomicAdd(&hist[b], 1);
        binned[base[b] + off] = pk[j];
    }
}

// pass B: one block per bucket. Pass 1: count per-node -> deg, dinv, rowptr (local scan).
// Pass 2: scatter binned entries into dense CSR order.
__global__ __launch_bounds__(256) void k_binB2(const unsigned* __restrict__ binned,
                                               const int* __restrict__ bucket_base,
                                               int* __restrict__ rowptr, float* __restrict__ dinv,
                                               int* __restrict__ csr_src, int n, int etot) {
    __shared__ int cur[512];
    __shared__ int lrp[512];
    __shared__ int ssum[256];
    int b = blockIdx.x, tid = threadIdx.x;
    int nstart = b << 9;
    int nn = min(512, n - nstart);
    int s0 = bucket_base[b], s1 = bucket_base[b + 1];
    cur[tid] = 0; cur[tid + 256] = 0;
    __syncthreads();
    for (int j = s0 + tid; j < s1; j += 256)
        atomicAdd(&cur[(binned[j] >> 17) & 511], 1);
    __syncthreads();
    int c0 = cur[2 * tid], c1 = cur[2 * tid + 1];
    int pair = c0 + c1;
    ssum[tid] = pair;
    __syncthreads();
    for (int off = 1; off < 256; off <<= 1) {
        int t2 = (tid >= off) ? ssum[tid - off] : 0;
        __syncthreads();
        ssum[tid] += t2;
        __syncthreads();
    }
    int e0 = ssum[tid] - pair;     // exclusive for elem 2t
    int e1 = e0 + c0;              // exclusive for elem 2t+1
    lrp[2 * tid] = s0 + e0;
    lrp[2 * tid + 1] = s0 + e1;
    if (2 * tid < nn) {
        rowptr[nstart + 2 * tid] = s0 + e0;
        dinv[nstart + 2 * tid] = rsqrtf((float)(c0 + 1));
    }
    if (2 * tid + 1 < nn) {
        rowptr[nstart + 2 * tid + 1] = s0 + e1;
        dinv[nstart + 2 * tid + 1] = rsqrtf((float)(c1 + 1));
    }
    if (tid == 255 && nstart + nn == n) rowptr[n] = etot;
    cur[2 * tid] = 0; cur[2 * tid + 1] = 0;
    __syncthreads();
    for (int j = s0 + tid; j < s1; j += 256) {
        unsigned p = binned[j];
        int nl = (p >> 17) & 511;
        int idx = atomicAdd(&cur[nl], 1);
        csr_src[lrp[nl] + idx] = p & 0x1ffff;
    }
}

// ---------------- dense kernels ----------------

// Build MFMA B-operand fragments from fp32 W[128][128] (row-major, W[k][n]).
// part 0 = bf16_hi(W), part 1 = bf16(W - hi)  (split for accuracy).
__global__ __launch_bounds__(256) void k_prepw(const float* __restrict__ W, uint4* __restrict__ Bf) {
    int id = blockIdx.x * 256 + threadIdx.x;   // 0..2047
    int lane = id & 63;
    int e = id >> 6;                            // 0..31
    int kk = e >> 3, c = e & 7;
    int kbase = kk * 32 + (lane >> 4) * 8;
    int col = c * 16 + (lane & 15);
    unsigned hi[8], lo[8];
    #pragma unroll
    for (int j = 0; j < 8; j++) {
        float w = W[(kbase + j) * 128 + col];
        unsigned h = bf16rne(w);
        float rh = __uint_as_float(h << 16);
        unsigned l = bf16rne(w - rh);
        hi[j] = h; lo[j] = l;
    }
    uint4 H = make_uint4(hi[0] | (hi[1] << 16), hi[2] | (hi[3] << 16),
                         hi[4] | (hi[5] << 16), hi[6] | (hi[7] << 16));
    uint4 L = make_uint4(lo[0] | (lo[1] << 16), lo[2] | (lo[3] << 16),
                         lo[4] | (lo[5] << 16), lo[6] | (lo[7] << 16));
    Bf[e * 64 + lane] = H;
    Bf[2048 + e * 64 + lane] = L;
}

// common MFMA GEMM body: a[4] fragments already loaded.
// Y[n,128](bf16) = A @ (Whi+Wlo). 512 threads = 8 waves, 128 rows/block.
static __device__ __forceinline__ void gemm_body(const uint4* __restrict__ Bfr, unsigned* __restrict__ Y,
                                                 int nrows, int rowbase, bfrag* a, uint4* bs) {
    int tid = threadIdx.x;
    int w = tid >> 6, lane = tid & 63;
    __syncthreads();   // bs staged
    f32x4 acc[8];
    #pragma unroll
    for (int c = 0; c < 8; c++) acc[c] = (f32x4){0.f, 0.f, 0.f, 0.f};
    #pragma unroll
    for (int kk = 0; kk < 4; kk++) {
        #pragma unroll
        for (int c = 0; c < 8; c++) {
            bfrag bh = *(const bfrag*)&bs[(kk * 8 + c) * 64 + lane];
            bfrag bl = *(const bfrag*)&bs[2048 + (kk * 8 + c) * 64 + lane];
            acc[c] = __builtin_amdgcn_mfma_f32_16x16x32_bf16(a[kk], bh, acc[c], 0, 0, 0);
            acc[c] = __builtin_amdgcn_mfma_f32_16x16x32_bf16(a[kk], bl, acc[c], 0, 0, 0);
        }
    }
    // epilogue: bounce through LDS (per-wave 16 x 136 ushorts) -> coalesced stores
    __syncthreads();
    char* epib = (char*)bs;
    ushort* epi = (ushort*)(epib + w * 4352);
    #pragma unroll
    for (int c = 0; c < 8; c++) {
        #pragma unroll
        for (int r = 0; r < 4; r++) {
            int rr = (lane >> 4) * 4 + r;
            epi[rr * 136 + c * 16 + (lane & 15)] = (ushort)bf16rne(acc[c][r]);
        }
    }
    __syncthreads();
    #pragma unroll
    for (int i = 0; i < 4; i++) {
        int id = tid + i * 512;
        int rr = id >> 4, q = id & 15;
        int grow = rowbase + rr;
        if (grow < nrows) {
            uint4 v = *(const uint4*)(epib + (rr >> 4) * 4352 + (rr & 15) * 272 + q * 16);
            ((uint4*)Y)[(size_t)grow * 16 + q] = v;
        }
    }
}

__global__ __launch_bounds__(512) void k_gemm_mfma(const unsigned* __restrict__ Xb,
                                                   const uint4* __restrict__ Bfr,
                                                   unsigned* __restrict__ Y, int nrows) {
    __shared__ uint4 bs[4096];                 // 64 KB
    int tid = threadIdx.x;
    int w = tid >> 6, lane = tid & 63;
    int rowbase = blockIdx.x * 128;
    #pragma unroll
    for (int i = 0; i < 8; i++) bs[tid + i * 512] = Bfr[tid + i * 512];
    int row = rowbase + w * 16 + (lane & 15);
    int rowc = min(row, nrows - 1);
    const uint4* X4 = (const uint4*)Xb;
    bfrag a[4];
    #pragma unroll
    for (int kk = 0; kk < 4; kk++) {
        uint4 av = X4[(size_t)rowc * 16 + kk * 4 + (lane >> 4)];
        a[kk] = *(const bfrag*)&av;
    }
    gemm_body(Bfr, Y, nrows, rowbase, a, bs);
}

// layer-1 variant: reads fp32 X, converts to bf16 fragments in-register.
__global__ __launch_bounds__(512) void k_gemm_mfma_f32(const float* __restrict__ X,
                                                       const uint4* __restrict__ Bfr,
                                                       unsigned* __restrict__ Y, int nrows) {
    __shared__ uint4 bs[4096];
    int tid = threadIdx.x;
    int w = tid >> 6, lane = tid & 63;
    int rowbase = blockIdx.x * 128;
    #pragma unroll
    for (int i = 0; i < 8; i++) bs[tid + i * 512] = Bfr[tid + i * 512];
    int row = rowbase + w * 16 + (lane & 15);
    int rowc = min(row, nrows - 1);
    const float4* X4 = (const float4*)X;
    bfrag a[4];
    #pragma unroll
    for (int kk = 0; kk < 4; kk++) {
        float4 f0 = X4[(size_t)rowc * 32 + kk * 8 + (lane >> 4) * 2];
        float4 f1 = X4[(size_t)rowc * 32 + kk * 8 + (lane >> 4) * 2 + 1];
        uint4 av = make_uint4(bf16rne(f0.x) | (bf16rne(f0.y) << 16),
                              bf16rne(f0.z) | (bf16rne(f0.w) << 16),
                              bf16rne(f1.x) | (bf16rne(f1.y) << 16),
                              bf16rne(f1.z) | (bf16rne(f1.w) << 16));
        a[kk] = *(const bfrag*)&av;
    }
    gemm_body(Bfr, Y, nrows, rowbase, a, bs);
}

// out[node](bf16) = relu(bn(segsum + bias)); 16 lanes per node, uint4/lane.
// 4 independent nodes per wave -> 4x gather MLP per load instruction.
__global__ __launch_bounds__(256) void k_aggregate(const uint4* __restrict__ H4, const int* __restrict__ rowptr,
                                                   const int* __restrict__ csr_src,
                                                   const float* __restrict__ dinv,
                                                   const float* __restrict__ bias, const float* __restrict__ gamma,
                                                   const float* __restrict__ beta,
                                                   uint4* __restrict__ out4, int nnodes) {
    int tid = blockIdx.x * 256 + threadIdx.x;
    int node = tid >> 4;
    int l = tid & 15;                    // cols 8l .. 8l+7
    if (node >= nnodes) return;
    float dn = dinv[node];
    float sl = dn * dn;
    float acc[8];
    {
        uint4 hv = H4[(size_t)node * 16 + l];
        acc[0] = bflo(hv.x) * sl; acc[1] = bfhi(hv.x) * sl;
        acc[2] = bflo(hv.y) * sl; acc[3] = bfhi(hv.y) * sl;
        acc[4] = bflo(hv.z) * sl; acc[5] = bfhi(hv.z) * sl;
        acc[6] = bflo(hv.w) * sl; acc[7] = bfhi(hv.w) * sl;
    }
    int s = rowptr[node], e = rowptr[node + 1];
    int j = s;
    for (; j + 3 < e; j += 4) {
        int s0 = csr_src[j], s1 = csr_src[j + 1], s2 = csr_src[j + 2], s3 = csr_src[j + 3];
        uint4 v0 = H4[(size_t)s0 * 16 + l];
        uint4 v1 = H4[(size_t)s1 * 16 + l];
        uint4 v2 = H4[(size_t)s2 * 16 + l];
        uint4 v3 = H4[(size_t)s3 * 16 + l];
        float n0 = dinv[s0] * dn, n1 = dinv[s1] * dn, n2 = dinv[s2] * dn, n3 = dinv[s3] * dn;
        acc[0] = fmaf(bflo(v0.x), n0, acc[0]); acc[1] = fmaf(bfhi(v0.x), n0, acc[1]);
        acc[2] = fmaf(bflo(v0.y), n0, acc[2]); acc[3] = fmaf(bfhi(v0.y), n0, acc[3]);
        acc[4] = fmaf(bflo(v0.z), n0, acc[4]); acc[5] = fmaf(bfhi(v0.z), n0, acc[5]);
        acc[6] = fmaf(bflo(v0.w), n0, acc[6]); acc[7] = fmaf(bfhi(v0.w), n0, acc[7]);
        acc[0] = fmaf(bflo(v1.x), n1, acc[0]); acc[1] = fmaf(bfhi(v1.x), n1, acc[1]);
        acc[2] = fmaf(bflo(v1.y), n1, acc[2]); acc[3] = fmaf(bfhi(v1.y), n1, acc[3]);
        acc[4] = fmaf(bflo(v1.z), n1, acc[4]); acc[5] = fmaf(bfhi(v1.z), n1, acc[5]);
        acc[6] = fmaf(bflo(v1.w), n1, acc[6]); acc[7] = fmaf(bfhi(v1.w), n1, acc[7]);
        acc[0] = fmaf(bflo(v2.x), n2, acc[0]); acc[1] = fmaf(bfhi(v2.x), n2, acc[1]);
        acc[2] = fmaf(bflo(v2.y), n2, acc[2]); acc[3] = fmaf(bfhi(v2.y), n2, acc[3]);
        acc[4] = fmaf(bflo(v2.z), n2, acc[4]); acc[5] = fmaf(bfhi(v2.z), n2, acc[5]);
        acc[6] = fmaf(bflo(v2.w), n2, acc[6]); acc[7] = fmaf(bfhi(v2.w), n2, acc[7]);
        acc[0] = fmaf(bflo(v3.x), n3, acc[0]); acc[1] = fmaf(bfhi(v3.x), n3, acc[1]);
        acc[2] = fmaf(bflo(v3.y), n3, acc[2]); acc[3] = fmaf(bfhi(v3.y), n3, acc[3]);
        acc[4] = fmaf(bflo(v3.z), n3, acc[4]); acc[5] = fmaf(bfhi(v3.z), n3, acc[5]);
        acc[6] = fmaf(bflo(v3.w), n3, acc[6]); acc[7] = fmaf(bfhi(v3.w), n3, acc[7]);
    }
    for (; j < e; j++) {
        int s0 = csr_src[j];
        uint4 v0 = H4[(size_t)s0 * 16 + l];
        float n0 = dinv[s0] * dn;
        acc[0] = fmaf(bflo(v0.x), n0, acc[0]); acc[1] = fmaf(bfhi(v0.x), n0, acc[1]);
        acc[2] = fmaf(bflo(v0.y), n0, acc[2]); acc[3] = fmaf(bfhi(v0.y), n0, acc[3]);
        acc[4] = fmaf(bflo(v0.z), n0, acc[4]); acc[5] = fmaf(bfhi(v0.z), n0, acc[5]);
        acc[6] = fmaf(bflo(v0.w), n0, acc[6]); acc[7] = fmaf(bfhi(v0.w), n0, acc[7]);
    }
    float4 bi0 = ((const float4*)bias)[l * 2],  bi1 = ((const float4*)bias)[l * 2 + 1];
    float4 ga0 = ((const float4*)gamma)[l * 2], ga1 = ((const float4*)gamma)[l * 2 + 1];
    float4 be0 = ((const float4*)beta)[l * 2],  be1 = ((const float4*)beta)[l * 2 + 1];
    float r[8];
    r[0] = fmaxf(fmaf(ga0.x * INV1P, acc[0] + bi0.x, be0.x), 0.f);
    r[1] = fmaxf(fmaf(ga0.y * INV1P, acc[1] + bi0.y, be0.y), 0.f);
    r[2] = fmaxf(fmaf(ga0.z * INV1P, acc[2] + bi0.z, be0.z), 0.f);
    r[3] = fmaxf(fmaf(ga0.w * INV1P, acc[3] + bi0.w, be0.w), 0.f);
    r[4] = fmaxf(fmaf(ga1.x * INV1P, acc[4] + bi1.x, be1.x), 0.f);
    r[5] = fmaxf(fmaf(ga1.y * INV1P, acc[5] + bi1.y, be1.y), 0.f);
    r[6] = fmaxf(fmaf(ga1.z * INV1P, acc[6] + bi1.z, be1.z), 0.f);
    r[7] = fmaxf(fmaf(ga1.w * INV1P, acc[7] + bi1.w, be1.w), 0.f);
    uint4 o;
    o.x = bf16rne(r[0]) | (bf16rne(r[1]) << 16);
    o.y = bf16rne(r[2]) | (bf16rne(r[3]) << 16);
    o.z = bf16rne(r[4]) | (bf16rne(r[5]) << 16);
    o.w = bf16rne(r[6]) | (bf16rne(r[7]) << 16);
    out4[(size_t)node * 16 + l] = o;
}

// pooled sums from bf16 H: 64 consecutive nodes per 64-thread block; batch sorted.
__global__ __launch_bounds__(64) void k_pool(const unsigned* __restrict__ Hf, const int* __restrict__ batch,
                                             float* __restrict__ pooled, float* __restrict__ cnt, int nnodes) {
    int t = threadIdx.x;
    int base = blockIdx.x * 64;
    if (base >= nnodes) return;
    int end = min(base + 64, nnodes);
    float ax = 0.f, ay = 0.f; int run = 0;
    int cur = batch[base];
    for (int i = base; i < end; i++) {
        int bg = batch[i];
        if (bg != cur) {
            atomicAdd(&pooled[(size_t)cur * 128 + 2 * t], ax);
            atomicAdd(&pooled[(size_t)cur * 128 + 2 * t + 1], ay);
            if (t == 0) atomicAdd(&cnt[cur], (float)run);
            ax = 0.f; ay = 0.f; run = 0; cur = bg;
        }
        unsigned u = Hf[(size_t)i * 64 + t];
        ax += bflo(u);
        ay += bfhi(u);
        run++;
    }
    atomicAdd(&pooled[(size_t)cur * 128 + 2 * t], ax);
    atomicAdd(&pooled[(size_t)cur * 128 + 2 * t + 1], ay);
    if (t == 0) atomicAdd(&cnt[cur], (float)run);
}

// classifier: one 64-thread block per graph. 128 -> 64 (relu) -> 10
__global__ __launch_bounds__(64) void k_classifier(const float* __restrict__ pooled, const float* __restrict__ cnt,
                                                   const float* __restrict__ Wc1, const float* __restrict__ bc1,
                                                   const float* __restrict__ Wc2, const float* __restrict__ bc2,
                                                   float* __restrict__ outp, int ngraphs) {
    __shared__ float p[128];
    __shared__ float z[64];
    int g = blockIdx.x;
    int tid = threadIdx.x;
    float inv = 1.0f / fmaxf(cnt[g], 1.0f);
    p[tid]      = pooled[(size_t)g * 128 + tid] * inv;
    p[tid + 64] = pooled[(size_t)g * 128 + 64 + tid] * inv;
    __syncthreads();
    float a = bc1[tid];
    #pragma unroll 8
    for (int k = 0; k < 128; k++) a += p[k] * Wc1[k * 64 + tid];
    z[tid] = fmaxf(a, 0.f);
    __syncthreads();
    if (tid < 10) {
        float o = bc2[tid];
        #pragma unroll 8
        for (int j = 0; j < 64; j++) o += z[j] * Wc2[j * 10 + tid];
        outp[(size_t)g * 10 + tid] = o;
    }
}

// ---------------- launch ----------------

static inline size_t align16(size_t v) { return (v + 15) & ~(size_t)15; }

extern "C" void kernel_launch(void* const* d_in, const int* in_sizes, int n_in,
                              void* d_out, int out_size, void* d_ws, size_t ws_size,
                              hipStream_t stream) {
    const float* x      = (const float*)d_in[0];
    const int*   ei     = (const int*)d_in[1];
    const int*   batch  = (const int*)d_in[2];
    const float* W1 = (const float*)d_in[3];  const float* b1 = (const float*)d_in[4];
    const float* W2 = (const float*)d_in[5];  const float* b2 = (const float*)d_in[6];
    const float* W3 = (const float*)d_in[7];  const float* b3 = (const float*)d_in[8];
    const float* g1 = (const float*)d_in[9];  const float* be1 = (const float*)d_in[10];
    const float* g2 = (const float*)d_in[11]; const float* be2 = (const float*)d_in[12];
    const float* g3 = (const float*)d_in[13]; const float* be3 = (const float*)d_in[14];
    const float* Wc1 = (const float*)d_in[15]; const float* bc1 = (const float*)d_in[16];
    const float* Wc2 = (const float*)d_in[17]; const float* bc2 = (const float*)d_in[18];

    const int N = in_sizes[0] / 128;
    const int E = in_sizes[1] / 2;
    const int G = out_size / 10;
    const int* srcp = ei;
    const int* dstp = ei + E;
    const int NB = (N + 511) >> 9;   // dst buckets of 512 nodes

    // workspace layout (16B-aligned slots)
    char* ws = (char*)d_ws;
    size_t off = 0;
    unsigned* bufA = (unsigned*)(ws + off); off = align16(off + (size_t)N * 64 * 4);
    unsigned* bufB = (unsigned*)(ws + off); off = align16(off + (size_t)N * 64 * 4);
    uint4* Bfr1 = (uint4*)(ws + off); off = align16(off + 4096 * 16);
    uint4* Bfr2 = (uint4*)(ws + off); off = align16(off + 4096 * 16);
    uint4* Bfr3 = (uint4*)(ws + off); off = align16(off + 4096 * 16);
    int*   csr_src = (int*)(ws + off);  off = align16(off + (size_t)E * 4);
    unsigned* binned = (unsigned*)(ws + off); off = align16(off + (size_t)E * 4);
    float* dinv   = (float*)(ws + off); off = align16(off + (size_t)N * 4);
    int*   rowptr = (int*)(ws + off);   off = align16(off + (size_t)(N + 1) * 4);
    int*   bucket_cnt  = (int*)(ws + off); off = align16(off + 256 * 4);
    int*   bucket_base = (int*)(ws + off); off = align16(off + 257 * 4);
    int*   gcursor = (int*)(ws + off);  off = align16(off + 256 * 4);
    float* pooled = (float*)(ws + off); off = align16(off + (size_t)G * 128 * 4);
    float* cnt    = (float*)(ws + off); off = align16(off + (size_t)G * 4);
    (void)ws_size;

    int gE8 = (E + 8191) / 8192;

    // weight prep (independent of graph structure)
    k_prepw<<<8, 256, 0, stream>>>(W1, Bfr1);
    k_prepw<<<8, 256, 0, stream>>>(W2, Bfr2);
    k_prepw<<<8, 256, 0, stream>>>(W3, Bfr3);

    // graph structure: atomic-free CSR build
    hipMemsetAsync(bucket_cnt, 0, 256 * 4, stream);
    k_bcount<<<gE8, 256, 0, stream>>>(dstp, bucket_cnt, E);
    k_bscan<<<1, 256, 0, stream>>>(bucket_cnt, bucket_base, gcursor, E);
    k_binA<<<gE8, 256, 0, stream>>>(srcp, dstp, gcursor, binned, E);
    k_binB2<<<NB, 256, 0, stream>>>(binned, bucket_base, rowptr, dinv, csr_src, N, E);

    int gGemm = (N + 127) / 128;
    int gAgg  = (N * 16 + 255) / 256;

    // layer 1 (fp32 input, in-register convert)
    k_gemm_mfma_f32<<<gGemm, 512, 0, stream>>>(x, Bfr1, bufA, N);
    k_aggregate<<<gAgg, 256, 0, stream>>>((const uint4*)bufA, rowptr, csr_src, dinv, b1, g1, be1, (uint4*)bufB, N);
    // layer 2
    k_gemm_mfma<<<gGemm, 512, 0, stream>>>(bufB, Bfr2, bufA, N);
    k_aggregate<<<gAgg, 256, 0, stream>>>((const uint4*)bufA, rowptr, csr_src, dinv, b2, g2, be2, (uint4*)bufB, N);
    // layer 3
    k_gemm_mfma<<<gGemm, 512, 0, stream>>>(bufB, Bfr3, bufA, N);
    k_aggregate<<<gAgg, 256, 0, stream>>>((const uint4*)bufA, rowptr, csr_src, dinv, b3, g3, be3, (uint4*)bufB, N);

    // pooling
    hipMemsetAsync(pooled, 0, ((size_t)G * 128 + G) * 4, stream);
    int gPool = (N + 63) / 64;
    k_pool<<<gPool, 64, 0, stream>>>(bufB, batch, pooled, cnt, N);

    // classifier
    k_classifier<<<G, 64, 0, stream>>>(pooled, cnt, Wc1, bc1, Wc2, bc2, (float*)d_out, G);
}

// Round 8
// 333.897 us; speedup vs baseline: 3.5153x; 1.0004x over previous
//
#include <hip/hip_runtime.h>
#include <hip/hip_bf16.h>

#define INV1P 0.9999950000374997f
#define BCAP 16384

typedef __attribute__((ext_vector_type(8))) short bfrag;   // 8 x bf16 (4 VGPR)
typedef __attribute__((ext_vector_type(4))) float f32x4;   // MFMA accumulator

static __device__ __forceinline__ unsigned bf16rne(float f) {
    unsigned u = __float_as_uint(f);
    return (u + 0x7fffu + ((u >> 16) & 1u)) >> 16;
}
static __device__ __forceinline__ float bflo(unsigned u) { return __uint_as_float(u << 16); }
static __device__ __forceinline__ float bfhi(unsigned u) { return __uint_as_float(u & 0xffff0000u); }

// ---------------- graph-structure kernels (atomic-free CSR build) ----------------

// gcursor[b] = b * BCAP  (over-allocated bucket regions in `binned`)
__global__ __launch_bounds__(256) void k_initcur2(int* __restrict__ gcursor) {
    gcursor[threadIdx.x] = threadIdx.x * BCAP;
}

// pass A: bin edges by dst-bucket. 8192 edges/block, packed (src | dst_low<<17).
__global__ __launch_bounds__(256) void k_binA(const int* __restrict__ src, const int* __restrict__ dst,
                                              int* __restrict__ gcursor, unsigned* __restrict__ binned, int e) {
    __shared__ unsigned pk[8192];
    __shared__ unsigned char bk[8192];
    __shared__ int hist[256];
    __shared__ int base[256];
    int tid = threadIdx.x;
    hist[tid] = 0;
    __syncthreads();
    int cbase = blockIdx.x * 8192;
    int cnt = min(8192, e - cbase);
    for (int j = tid; j < cnt; j += 256) {
        int s = src[cbase + j], d = dst[cbase + j];
        unsigned b = (unsigned)d >> 9;
        pk[j] = (unsigned)s | (((unsigned)d & 511u) << 17);
        bk[j] = (unsigned char)b;
        atomicAdd(&hist[b], 1);
    }
    __syncthreads();
    int h = hist[tid];
    base[tid] = (h > 0) ? atomicAdd(&gcursor[tid], h) : 0;
    hist[tid] = 0;
    __syncthreads();
    for (int j = tid; j < cnt; j += 256) {
        unsigned b = bk[j];
        int off = atomicAdd(&hist[b], 1);
        binned[base[b] + off] = pk[j];
    }
}

// after binA: 1-block scan of actual bucket counts -> bucket_base[257]
__global__ __launch_bounds__(256) void k_bscan2(const int* __restrict__ gcursor, int* __restrict__ bucket_base,
                                                int nbuckets, int etot) {
    __shared__ int sh[256];
    int tid = threadIdx.x;
    int v = (tid < nbuckets) ? (gcursor[tid] - tid * BCAP) : 0;
    sh[tid] = v; __syncthreads();
    for (int off = 1; off < 256; off <<= 1) {
        int t2 = (tid >= off) ? sh[tid - off] : 0;
        __syncthreads();
        sh[tid] += t2;
        __syncthreads();
    }
    bucket_base[tid] = sh[tid] - v;   // exclusive
    if (tid == 255) bucket_base[256] = etot;
}

// pass B: one block per bucket. Pass 1: count per-node -> dinv, rowptr (local scan).
// Pass 2: scatter binned entries into dense CSR order.
__global__ __launch_bounds__(256) void k_binB2(const unsigned* __restrict__ binned,
                                               const int* __restrict__ bucket_base,
                                               int* __restrict__ rowptr, float* __restrict__ dinv,
                                               int* __restrict__ csr_src, int n, int etot) {
    __shared__ int cur[512];
    __shared__ int lrp[512];
    __shared__ int ssum[256];
    int b = blockIdx.x, tid = threadIdx.x;
    int nstart = b << 9;
    int nn = min(512, n - nstart);
    int cb = bucket_base[b];
    int cntb = bucket_base[b + 1] - cb;
    int s0 = b * BCAP, s1 = s0 + cntb;
    cur[tid] = 0; cur[tid + 256] = 0;
    __syncthreads();
    for (int j = s0 + tid; j < s1; j += 256)
        atomicAdd(&cur[(binned[j] >> 17) & 511], 1);
    __syncthreads();
    int c0 = cur[2 * tid], c1 = cur[2 * tid + 1];
    int pair = c0 + c1;
    ssum[tid] = pair;
    __syncthreads();
    for (int off = 1; off < 256; off <<= 1) {
        int t2 = (tid >= off) ? ssum[tid - off] : 0;
        __syncthreads();
        ssum[tid] += t2;
        __syncthreads();
    }
    int e0 = ssum[tid] - pair;     // exclusive for elem 2t
    int e1 = e0 + c0;              // exclusive for elem 2t+1
    lrp[2 * tid] = cb + e0;
    lrp[2 * tid + 1] = cb + e1;
    if (2 * tid < nn) {
        rowptr[nstart + 2 * tid] = cb + e0;
        dinv[nstart + 2 * tid] = rsqrtf((float)(c0 + 1));
    }
    if (2 * tid + 1 < nn) {
        rowptr[nstart + 2 * tid + 1] = cb + e1;
        dinv[nstart + 2 * tid + 1] = rsqrtf((float)(c1 + 1));
    }
    if (tid == 255 && nstart + nn == n) rowptr[n] = etot;
    cur[2 * tid] = 0; cur[2 * tid + 1] = 0;
    __syncthreads();
    for (int j = s0 + tid; j < s1; j += 256) {
        unsigned p = binned[j];
        int nl = (p >> 17) & 511;
        int idx = atomicAdd(&cur[nl], 1);
        csr_src[lrp[nl] + idx] = p & 0x1ffff;
    }
}

// ---------------- dense kernels ----------------

// Build MFMA B-operand fragments from fp32 W[128][128] (row-major, W[k][n]).
// part 0 = bf16_hi(W), part 1 = bf16(W - hi)  (split for accuracy).
__global__ __launch_bounds__(256) void k_prepw(const float* __restrict__ W, uint4* __restrict__ Bf) {
    int id = blockIdx.x * 256 + threadIdx.x;   // 0..2047
    int lane = id & 63;
    int e = id >> 6;                            // 0..31
    int kk = e >> 3, c = e & 7;
    int kbase = kk * 32 + (lane >> 4) * 8;
    int col = c * 16 + (lane & 15);
    unsigned hi[8], lo[8];
    #pragma unroll
    for (int j = 0; j < 8; j++) {
        float w = W[(kbase + j) * 128 + col];
        unsigned h = bf16rne(w);
        float rh = __uint_as_float(h << 16);
        unsigned l = bf16rne(w - rh);
        hi[j] = h; lo[j] = l;
    }
    uint4 H = make_uint4(hi[0] | (hi[1] << 16), hi[2] | (hi[3] << 16),
                         hi[4] | (hi[5] << 16), hi[6] | (hi[7] << 16));
    uint4 L = make_uint4(lo[0] | (lo[1] << 16), lo[2] | (lo[3] << 16),
                         lo[4] | (lo[5] << 16), lo[6] | (lo[7] << 16));
    Bf[e * 64 + lane] = H;
    Bf[2048 + e * 64 + lane] = L;
}

// common MFMA GEMM body: a[4] fragments already loaded.
// Y'[n,128](bf16) = (A @ (Whi+Wlo)) * dinv[row]. 512 threads = 8 waves, 128 rows/block.
static __device__ __forceinline__ void gemm_body(unsigned* __restrict__ Y, const float* __restrict__ dinv,
                                                 int nrows, int rowbase, bfrag* a, uint4* bs) {
    int tid = threadIdx.x;
    int w = tid >> 6, lane = tid & 63;
    __syncthreads();   // bs staged
    f32x4 acc[8];
    #pragma unroll
    for (int c = 0; c < 8; c++) acc[c] = (f32x4){0.f, 0.f, 0.f, 0.f};
    #pragma unroll
    for (int kk = 0; kk < 4; kk++) {
        #pragma unroll
        for (int c = 0; c < 8; c++) {
            bfrag bh = *(const bfrag*)&bs[(kk * 8 + c) * 64 + lane];
            bfrag bl = *(const bfrag*)&bs[2048 + (kk * 8 + c) * 64 + lane];
            acc[c] = __builtin_amdgcn_mfma_f32_16x16x32_bf16(a[kk], bh, acc[c], 0, 0, 0);
            acc[c] = __builtin_amdgcn_mfma_f32_16x16x32_bf16(a[kk], bl, acc[c], 0, 0, 0);
        }
    }
    // per-row dinv scale (pre-scales Y so aggregate needs no src-norm gather)
    int rb = rowbase + w * 16 + (lane >> 4) * 4;
    float dv[4];
    #pragma unroll
    for (int r = 0; r < 4; r++) dv[r] = dinv[min(rb + r, nrows - 1)];
    // epilogue: bounce through LDS (per-wave 16 x 136 ushorts) -> coalesced stores
    __syncthreads();
    char* epib = (char*)bs;
    ushort* epi = (ushort*)(epib + w * 4352);
    #pragma unroll
    for (int c = 0; c < 8; c++) {
        #pragma unroll
        for (int r = 0; r < 4; r++) {
            int rr = (lane >> 4) * 4 + r;
            epi[rr * 136 + c * 16 + (lane & 15)] = (ushort)bf16rne(acc[c][r] * dv[r]);
        }
    }
    __syncthreads();
    #pragma unroll
    for (int i = 0; i < 4; i++) {
        int id = tid + i * 512;
        int rr = id >> 4, q = id & 15;
        int grow = rowbase + rr;
        if (grow < nrows) {
            uint4 v = *(const uint4*)(epib + (rr >> 4) * 4352 + (rr & 15) * 272 + q * 16);
            ((uint4*)Y)[(size_t)grow * 16 + q] = v;
        }
    }
}

__global__ __launch_bounds__(512) void k_gemm_mfma(const unsigned* __restrict__ Xb,
                                                   const uint4* __restrict__ Bfr,
                                                   unsigned* __restrict__ Y, const float* __restrict__ dinv,
                                                   int nrows) {
    __shared__ uint4 bs[4096];                 // 64 KB
    int tid = threadIdx.x;
    int w = tid >> 6, lane = tid & 63;
    int rowbase = blockIdx.x * 128;
    #pragma unroll
    for (int i = 0; i < 8; i++) bs[tid + i * 512] = Bfr[tid + i * 512];
    int row = rowbase + w * 16 + (lane & 15);
    int rowc = min(row, nrows - 1);
    const uint4* X4 = (const uint4*)Xb;
    bfrag a[4];
    #pragma unroll
    for (int kk = 0; kk < 4; kk++) {
        uint4 av = X4[(size_t)rowc * 16 + kk * 4 + (lane >> 4)];
        a[kk] = *(const bfrag*)&av;
    }
    gemm_body(Y, dinv, nrows, rowbase, a, bs);
}

// layer-1 variant: reads fp32 X, converts to bf16 fragments in-register.
__global__ __launch_bounds__(512) void k_gemm_mfma_f32(const float* __restrict__ X,
                                                       const uint4* __restrict__ Bfr,
                                                       unsigned* __restrict__ Y, const float* __restrict__ dinv,
                                                       int nrows) {
    __shared__ uint4 bs[4096];
    int tid = threadIdx.x;
    int w = tid >> 6, lane = tid & 63;
    int rowbase = blockIdx.x * 128;
    #pragma unroll
    for (int i = 0; i < 8; i++) bs[tid + i * 512] = Bfr[tid + i * 512];
    int row = rowbase + w * 16 + (lane & 15);
    int rowc = min(row, nrows - 1);
    const float4* X4 = (const float4*)X;
    bfrag a[4];
    #pragma unroll
    for (int kk = 0; kk < 4; kk++) {
        float4 f0 = X4[(size_t)rowc * 32 + kk * 8 + (lane >> 4) * 2];
        float4 f1 = X4[(size_t)rowc * 32 + kk * 8 + (lane >> 4) * 2 + 1];
        uint4 av = make_uint4(bf16rne(f0.x) | (bf16rne(f0.y) << 16),
                              bf16rne(f0.z) | (bf16rne(f0.w) << 16),
                              bf16rne(f1.x) | (bf16rne(f1.y) << 16),
                              bf16rne(f1.z) | (bf16rne(f1.w) << 16));
        a[kk] = *(const bfrag*)&av;
    }
    gemm_body(Y, dinv, nrows, rowbase, a, bs);
}

// out[node](bf16) = relu(bn(dinv[dst]*(sum Y'[src] + Y'[dst]) + bias));
// Y' pre-scaled by dinv[src]. 16 lanes per node, uint4/lane, 8-deep unroll.
__global__ __launch_bounds__(256) void k_aggregate(const uint4* __restrict__ H4, const int* __restrict__ rowptr,
                                                   const int* __restrict__ csr_src,
                                                   const float* __restrict__ dinv,
                                                   const float* __restrict__ bias, const float* __restrict__ gamma,
                                                   const float* __restrict__ beta,
                                                   uint4* __restrict__ out4, int nnodes) {
    int tid = blockIdx.x * 256 + threadIdx.x;
    int node = tid >> 4;
    int l = tid & 15;                    // cols 8l .. 8l+7
    if (node >= nnodes) return;
    float acc[8];
    {
        uint4 hv = H4[(size_t)node * 16 + l];   // Y'[dst] (self term, pre-scaled)
        acc[0] = bflo(hv.x); acc[1] = bfhi(hv.x);
        acc[2] = bflo(hv.y); acc[3] = bfhi(hv.y);
        acc[4] = bflo(hv.z); acc[5] = bfhi(hv.z);
        acc[6] = bflo(hv.w); acc[7] = bfhi(hv.w);
    }
    int s = rowptr[node], e = rowptr[node + 1];
    int j = s;
    for (; j + 7 < e; j += 8) {
        uint4 vv[8];
        #pragma unroll
        for (int q = 0; q < 8; q++) {
            int sv = csr_src[j + q];
            vv[q] = H4[(size_t)sv * 16 + l];
        }
        #pragma unroll
        for (int q = 0; q < 8; q++) {
            acc[0] += bflo(vv[q].x); acc[1] += bfhi(vv[q].x);
            acc[2] += bflo(vv[q].y); acc[3] += bfhi(vv[q].y);
            acc[4] += bflo(vv[q].z); acc[5] += bfhi(vv[q].z);
            acc[6] += bflo(vv[q].w); acc[7] += bfhi(vv[q].w);
        }
    }
    for (; j < e; j++) {
        int sv = csr_src[j];
        uint4 v0 = H4[(size_t)sv * 16 + l];
        acc[0] += bflo(v0.x); acc[1] += bfhi(v0.x);
        acc[2] += bflo(v0.y); acc[3] += bfhi(v0.y);
        acc[4] += bflo(v0.z); acc[5] += bfhi(v0.z);
        acc[6] += bflo(v0.w); acc[7] += bfhi(v0.w);
    }
    float dn = dinv[node];
    float4 bi0 = ((const float4*)bias)[l * 2],  bi1 = ((const float4*)bias)[l * 2 + 1];
    float4 ga0 = ((const float4*)gamma)[l * 2], ga1 = ((const float4*)gamma)[l * 2 + 1];
    float4 be0 = ((const float4*)beta)[l * 2],  be1 = ((const float4*)beta)[l * 2 + 1];
    float g[8] = {ga0.x, ga0.y, ga0.z, ga0.w, ga1.x, ga1.y, ga1.z, ga1.w};
    float bb[8] = {bi0.x, bi0.y, bi0.z, bi0.w, bi1.x, bi1.y, bi1.z, bi1.w};
    float bt[8] = {be0.x, be0.y, be0.z, be0.w, be1.x, be1.y, be1.z, be1.w};
    float r[8];
    #pragma unroll
    for (int i = 0; i < 8; i++) {
        float t = g[i] * INV1P;
        r[i] = fmaxf(fmaf(t * dn, acc[i], fmaf(t, bb[i], bt[i])), 0.f);
    }
    uint4 o;
    o.x = bf16rne(r[0]) | (bf16rne(r[1]) << 16);
    o.y = bf16rne(r[2]) | (bf16rne(r[3]) << 16);
    o.z = bf16rne(r[4]) | (bf16rne(r[5]) << 16);
    o.w = bf16rne(r[6]) | (bf16rne(r[7]) << 16);
    out4[(size_t)node * 16 + l] = o;
}

// pooled sums from bf16 H: 64 consecutive nodes per 64-thread block; batch sorted.
__global__ __launch_bounds__(64) void k_pool(const unsigned* __restrict__ Hf, const int* __restrict__ batch,
                                             float* __restrict__ pooled, float* __restrict__ cnt, int nnodes) {
    int t = threadIdx.x;
    int base = blockIdx.x * 64;
    if (base >= nnodes) return;
    int end = min(base + 64, nnodes);
    float ax = 0.f, ay = 0.f; int run = 0;
    int cur = batch[base];
    for (int i = base; i < end; i++) {
        int bg = batch[i];
        if (bg != cur) {
            atomicAdd(&pooled[(size_t)cur * 128 + 2 * t], ax);
            atomicAdd(&pooled[(size_t)cur * 128 + 2 * t + 1], ay);
            if (t == 0) atomicAdd(&cnt[cur], (float)run);
            ax = 0.f; ay = 0.f; run = 0; cur = bg;
        }
        unsigned u = Hf[(size_t)i * 64 + t];
        ax += bflo(u);
        ay += bfhi(u);
        run++;
    }
    atomicAdd(&pooled[(size_t)cur * 128 + 2 * t], ax);
    atomicAdd(&pooled[(size_t)cur * 128 + 2 * t + 1], ay);
    if (t == 0) atomicAdd(&cnt[cur], (float)run);
}

// classifier: one 64-thread block per graph. 128 -> 64 (relu) -> 10
__global__ __launch_bounds__(64) void k_classifier(const float* __restrict__ pooled, const float* __restrict__ cnt,
                                                   const float* __restrict__ Wc1, const float* __restrict__ bc1,
                                                   const float* __restrict__ Wc2, const float* __restrict__ bc2,
                                                   float* __restrict__ outp, int ngraphs) {
    __shared__ float p[128];
    __shared__ float z[64];
    int g = blockIdx.x;
    int tid = threadIdx.x;
    float inv = 1.0f / fmaxf(cnt[g], 1.0f);
    p[tid]      = pooled[(size_t)g * 128 + tid] * inv;
    p[tid + 64] = pooled[(size_t)g * 128 + 64 + tid] * inv;
    __syncthreads();
    float a = bc1[tid];
    #pragma unroll 8
    for (int k = 0; k < 128; k++) a += p[k] * Wc1[k * 64 + tid];
    z[tid] = fmaxf(a, 0.f);
    __syncthreads();
    if (tid < 10) {
        float o = bc2[tid];
        #pragma unroll 8
        for (int j = 0; j < 64; j++) o += z[j] * Wc2[j * 10 + tid];
        outp[(size_t)g * 10 + tid] = o;
    }
}

// ---------------- launch ----------------

static inline size_t align16(size_t v) { return (v + 15) & ~(size_t)15; }

extern "C" void kernel_launch(void* const* d_in, const int* in_sizes, int n_in,
                              void* d_out, int out_size, void* d_ws, size_t ws_size,
                              hipStream_t stream) {
    const float* x      = (const float*)d_in[0];
    const int*   ei     = (const int*)d_in[1];
    const int*   batch  = (const int*)d_in[2];
    const float* W1 = (const float*)d_in[3];  const float* b1 = (const float*)d_in[4];
    const float* W2 = (const float*)d_in[5];  const float* b2 = (const float*)d_in[6];
    const float* W3 = (const float*)d_in[7];  const float* b3 = (const float*)d_in[8];
    const float* g1 = (const float*)d_in[9];  const float* be1 = (const float*)d_in[10];
    const float* g2 = (const float*)d_in[11]; const float* be2 = (const float*)d_in[12];
    const float* g3 = (const float*)d_in[13]; const float* be3 = (const float*)d_in[14];
    const float* Wc1 = (const float*)d_in[15]; const float* bc1 = (const float*)d_in[16];
    const float* Wc2 = (const float*)d_in[17]; const float* bc2 = (const float*)d_in[18];

    const int N = in_sizes[0] / 128;
    const int E = in_sizes[1] / 2;
    const int G = out_size / 10;
    const int* srcp = ei;
    const int* dstp = ei + E;
    const int NB = (N + 511) >> 9;   // dst buckets of 512 nodes

    // workspace layout (16B-aligned slots)
    char* ws = (char*)d_ws;
    size_t off = 0;
    unsigned* bufA = (unsigned*)(ws + off); off = align16(off + (size_t)N * 64 * 4);
    unsigned* bufB = (unsigned*)(ws + off); off = align16(off + (size_t)N * 64 * 4);
    uint4* Bfr1 = (uint4*)(ws + off); off = align16(off + 4096 * 16);
    uint4* Bfr2 = (uint4*)(ws + off); off = align16(off + 4096 * 16);
    uint4* Bfr3 = (uint4*)(ws + off); off = align16(off + 4096 * 16);
    int*   csr_src = (int*)(ws + off);  off = align16(off + (size_t)E * 4);
    unsigned* binned = (unsigned*)(ws + off); off = align16(off + ((size_t)NB * BCAP + (size_t)E) * 4);
    float* dinv   = (float*)(ws + off); off = align16(off + (size_t)N * 4);
    int*   rowptr = (int*)(ws + off);   off = align16(off + (size_t)(N + 1) * 4);
    int*   bucket_base = (int*)(ws + off); off = align16(off + 257 * 4);
    int*   gcursor = (int*)(ws + off);  off = align16(off + 256 * 4);
    float* pooled = (float*)(ws + off); off = align16(off + (size_t)G * 128 * 4);
    float* cnt    = (float*)(ws + off); off = align16(off + (size_t)G * 4);
    (void)ws_size;

    int gE8 = (E + 8191) / 8192;

    // weight prep (independent of graph structure)
    k_prepw<<<8, 256, 0, stream>>>(W1, Bfr1);
    k_prepw<<<8, 256, 0, stream>>>(W2, Bfr2);
    k_prepw<<<8, 256, 0, stream>>>(W3, Bfr3);

    // graph structure: atomic-free CSR build (over-allocated buckets, post-scan)
    k_initcur2<<<1, 256, 0, stream>>>(gcursor);
    k_binA<<<gE8, 256, 0, stream>>>(srcp, dstp, gcursor, binned, E);
    k_bscan2<<<1, 256, 0, stream>>>(gcursor, bucket_base, NB, E);
    k_binB2<<<NB, 256, 0, stream>>>(binned, bucket_base, rowptr, dinv, csr_src, N, E);

    int gGemm = (N + 127) / 128;
    int gAgg  = (N * 16 + 255) / 256;

    // layer 1 (fp32 input, in-register convert)
    k_gemm_mfma_f32<<<gGemm, 512, 0, stream>>>(x, Bfr1, bufA, dinv, N);
    k_aggregate<<<gAgg, 256, 0, stream>>>((const uint4*)bufA, rowptr, csr_src, dinv, b1, g1, be1, (uint4*)bufB, N);
    // layer 2
    k_gemm_mfma<<<gGemm, 512, 0, stream>>>(bufB, Bfr2, bufA, dinv, N);
    k_aggregate<<<gAgg, 256, 0, stream>>>((const uint4*)bufA, rowptr, csr_src, dinv, b2, g2, be2, (uint4*)bufB, N);
    // layer 3
    k_gemm_mfma<<<gGemm, 512, 0, stream>>>(bufB, Bfr3, bufA, dinv, N);
    k_aggregate<<<gAgg, 256, 0, stream>>>((const uint4*)bufA, rowptr, csr_src, dinv, b3, g3, be3, (uint4*)bufB, N);

    // pooling
    hipMemsetAsync(pooled, 0, ((size_t)G * 128 + G) * 4, stream);
    int gPool = (N + 63) / 64;
    k_pool<<<gPool, 64, 0, stream>>>(bufB, batch, pooled, cnt, N);

    // classifier
    k_classifier<<<G, 64, 0, stream>>>(pooled, cnt, Wc1, bc1, Wc2, bc2, (float*)d_out, G);
}

// Round 9
// 312.015 us; speedup vs baseline: 3.7619x; 1.0701x over previous
//
#include <hip/hip_runtime.h>
#include <hip/hip_bf16.h>

#define INV1P 0.9999950000374997f
#define BCAP 16384
#define CSRCAP 20480

typedef __attribute__((ext_vector_type(8))) short bfrag;   // 8 x bf16 (4 VGPR)
typedef __attribute__((ext_vector_type(4))) float f32x4;   // MFMA accumulator

static __device__ __forceinline__ unsigned bf16rne(float f) {
    unsigned u = __float_as_uint(f);
    return (u + 0x7fffu + ((u >> 16) & 1u)) >> 16;
}
static __device__ __forceinline__ float bflo(unsigned u) { return __uint_as_float(u << 16); }
static __device__ __forceinline__ float bfhi(unsigned u) { return __uint_as_float(u & 0xffff0000u); }

// ---------------- graph-structure kernels (atomic-free CSR build) ----------------

// gcursor[b] = b * BCAP  (over-allocated bucket regions in `binned`)
__global__ __launch_bounds__(256) void k_initcur2(int* __restrict__ gcursor) {
    gcursor[threadIdx.x] = threadIdx.x * BCAP;
}

// pass A: bin edges by dst-bucket. 8192 edges/block, packed (src | dst_low<<17).
__global__ __launch_bounds__(256) void k_binA(const int* __restrict__ src, const int* __restrict__ dst,
                                              int* __restrict__ gcursor, unsigned* __restrict__ binned, int e) {
    __shared__ unsigned pk[8192];
    __shared__ unsigned char bk[8192];
    __shared__ int hist[256];
    __shared__ int base[256];
    int tid = threadIdx.x;
    hist[tid] = 0;
    __syncthreads();
    int cbase = blockIdx.x * 8192;
    int cnt = min(8192, e - cbase);
    for (int j = tid; j < cnt; j += 256) {
        int s = src[cbase + j], d = dst[cbase + j];
        unsigned b = (unsigned)d >> 9;
        pk[j] = (unsigned)s | (((unsigned)d & 511u) << 17);
        bk[j] = (unsigned char)b;
        atomicAdd(&hist[b], 1);
    }
    __syncthreads();
    int h = hist[tid];
    base[tid] = (h > 0) ? atomicAdd(&gcursor[tid], h) : 0;
    hist[tid] = 0;
    __syncthreads();
    for (int j = tid; j < cnt; j += 256) {
        unsigned b = bk[j];
        int off = atomicAdd(&hist[b], 1);
        binned[base[b] + off] = pk[j];
    }
}

// pass B: one block per bucket. Pass 1: count per-node -> dinv, rowptr/rowend
// (padded to multiple of 8, pad slots = dummy index). Pass 2: scatter to CSR.
__global__ __launch_bounds__(256) void k_binB2(const unsigned* __restrict__ binned,
                                               const int* __restrict__ gcursor,
                                               int* __restrict__ rowptr, int* __restrict__ rowend,
                                               float* __restrict__ dinv,
                                               int* __restrict__ csr_src, int n, int dummy) {
    __shared__ int cur[512];
    __shared__ int lrp[512];
    __shared__ int ssum[256];
    int b = blockIdx.x, tid = threadIdx.x;
    int nstart = b << 9;
    int nn = min(512, n - nstart);
    int cntb = gcursor[b] - b * BCAP;
    int s0 = b * BCAP, s1 = s0 + cntb;
    int cb = b * CSRCAP;
    cur[tid] = 0; cur[tid + 256] = 0;
    __syncthreads();
    for (int j = s0 + tid; j < s1; j += 256)
        atomicAdd(&cur[(binned[j] >> 17) & 511], 1);
    __syncthreads();
    int c0 = cur[2 * tid], c1 = cur[2 * tid + 1];
    int p0 = (c0 + 7) & ~7, p1 = (c1 + 7) & ~7;
    int pair = p0 + p1;
    ssum[tid] = pair;
    __syncthreads();
    for (int off = 1; off < 256; off <<= 1) {
        int t2 = (tid >= off) ? ssum[tid - off] : 0;
        __syncthreads();
        ssum[tid] += t2;
        __syncthreads();
    }
    int e0 = ssum[tid] - pair;     // exclusive (padded) for elem 2t
    int e1 = e0 + p0;
    int st0 = cb + e0, st1 = cb + e1;
    lrp[2 * tid] = st0;
    lrp[2 * tid + 1] = st1;
    if (2 * tid < nn) {
        rowptr[nstart + 2 * tid] = st0;
        rowend[nstart + 2 * tid] = st0 + p0;
        dinv[nstart + 2 * tid] = rsqrtf((float)(c0 + 1));
    }
    if (2 * tid + 1 < nn) {
        rowptr[nstart + 2 * tid + 1] = st1;
        rowend[nstart + 2 * tid + 1] = st1 + p1;
        dinv[nstart + 2 * tid + 1] = rsqrtf((float)(c1 + 1));
    }
    // pad-fill with dummy index (zero row in H)
    for (int k = c0; k < p0; k++) csr_src[st0 + k] = dummy;
    for (int k = c1; k < p1; k++) csr_src[st1 + k] = dummy;
    cur[2 * tid] = 0; cur[2 * tid + 1] = 0;
    __syncthreads();
    for (int j = s0 + tid; j < s1; j += 256) {
        unsigned p = binned[j];
        int nl = (p >> 17) & 511;
        int idx = atomicAdd(&cur[nl], 1);
        csr_src[lrp[nl] + idx] = p & 0x1ffff;
    }
}

// ---------------- dense kernels ----------------

// Build MFMA B-operand fragments from fp32 W[128][128] (row-major, W[k][n]).
// part 0 = bf16_hi(W), part 1 = bf16(W - hi)  (split for accuracy).
__global__ __launch_bounds__(256) void k_prepw(const float* __restrict__ W, uint4* __restrict__ Bf) {
    int id = blockIdx.x * 256 + threadIdx.x;   // 0..2047
    int lane = id & 63;
    int e = id >> 6;                            // 0..31
    int kk = e >> 3, c = e & 7;
    int kbase = kk * 32 + (lane >> 4) * 8;
    int col = c * 16 + (lane & 15);
    unsigned hi[8], lo[8];
    #pragma unroll
    for (int j = 0; j < 8; j++) {
        float w = W[(kbase + j) * 128 + col];
        unsigned h = bf16rne(w);
        float rh = __uint_as_float(h << 16);
        unsigned l = bf16rne(w - rh);
        hi[j] = h; lo[j] = l;
    }
    uint4 H = make_uint4(hi[0] | (hi[1] << 16), hi[2] | (hi[3] << 16),
                         hi[4] | (hi[5] << 16), hi[6] | (hi[7] << 16));
    uint4 L = make_uint4(lo[0] | (lo[1] << 16), lo[2] | (lo[3] << 16),
                         lo[4] | (lo[5] << 16), lo[6] | (lo[7] << 16));
    Bf[e * 64 + lane] = H;
    Bf[2048 + e * 64 + lane] = L;
}

// common MFMA GEMM body: a[4] fragments already loaded.
// Y'[n,128](bf16) = (A @ (Whi+Wlo)) * dinv[row]. 512 threads = 8 waves, 128 rows/block.
static __device__ __forceinline__ void gemm_body(unsigned* __restrict__ Y, const float* __restrict__ dinv,
                                                 int nrows, int rowbase, bfrag* a, uint4* bs) {
    int tid = threadIdx.x;
    int w = tid >> 6, lane = tid & 63;
    __syncthreads();   // bs staged
    f32x4 acc[8];
    #pragma unroll
    for (int c = 0; c < 8; c++) acc[c] = (f32x4){0.f, 0.f, 0.f, 0.f};
    #pragma unroll
    for (int kk = 0; kk < 4; kk++) {
        #pragma unroll
        for (int c = 0; c < 8; c++) {
            bfrag bh = *(const bfrag*)&bs[(kk * 8 + c) * 64 + lane];
            bfrag bl = *(const bfrag*)&bs[2048 + (kk * 8 + c) * 64 + lane];
            acc[c] = __builtin_amdgcn_mfma_f32_16x16x32_bf16(a[kk], bh, acc[c], 0, 0, 0);
            acc[c] = __builtin_amdgcn_mfma_f32_16x16x32_bf16(a[kk], bl, acc[c], 0, 0, 0);
        }
    }
    // per-row dinv scale (pre-scales Y so aggregate needs no src-norm gather)
    int rb = rowbase + w * 16 + (lane >> 4) * 4;
    float dv[4];
    #pragma unroll
    for (int r = 0; r < 4; r++) dv[r] = dinv[min(rb + r, nrows - 1)];
    // epilogue: bounce through LDS (per-wave 16 x 136 ushorts) -> coalesced stores
    __syncthreads();
    char* epib = (char*)bs;
    ushort* epi = (ushort*)(epib + w * 4352);
    #pragma unroll
    for (int c = 0; c < 8; c++) {
        #pragma unroll
        for (int r = 0; r < 4; r++) {
            int rr = (lane >> 4) * 4 + r;
            epi[rr * 136 + c * 16 + (lane & 15)] = (ushort)bf16rne(acc[c][r] * dv[r]);
        }
    }
    __syncthreads();
    #pragma unroll
    for (int i = 0; i < 4; i++) {
        int id = tid + i * 512;
        int rr = id >> 4, q = id & 15;
        int grow = rowbase + rr;
        if (grow < nrows) {
            uint4 v = *(const uint4*)(epib + (rr >> 4) * 4352 + (rr & 15) * 272 + q * 16);
            ((uint4*)Y)[(size_t)grow * 16 + q] = v;
        }
    }
}

__global__ __launch_bounds__(512) void k_gemm_mfma(const unsigned* __restrict__ Xb,
                                                   const uint4* __restrict__ Bfr,
                                                   unsigned* __restrict__ Y, const float* __restrict__ dinv,
                                                   int nrows) {
    __shared__ uint4 bs[4096];                 // 64 KB
    int tid = threadIdx.x;
    int w = tid >> 6, lane = tid & 63;
    int rowbase = blockIdx.x * 128;
    #pragma unroll
    for (int i = 0; i < 8; i++) bs[tid + i * 512] = Bfr[tid + i * 512];
    int row = rowbase + w * 16 + (lane & 15);
    int rowc = min(row, nrows - 1);
    const uint4* X4 = (const uint4*)Xb;
    bfrag a[4];
    #pragma unroll
    for (int kk = 0; kk < 4; kk++) {
        uint4 av = X4[(size_t)rowc * 16 + kk * 4 + (lane >> 4)];
        a[kk] = *(const bfrag*)&av;
    }
    gemm_body(Y, dinv, nrows, rowbase, a, bs);
}

// layer-1 variant: reads fp32 X, converts to bf16 fragments in-register.
__global__ __launch_bounds__(512) void k_gemm_mfma_f32(const float* __restrict__ X,
                                                       const uint4* __restrict__ Bfr,
                                                       unsigned* __restrict__ Y, const float* __restrict__ dinv,
                                                       int nrows) {
    __shared__ uint4 bs[4096];
    int tid = threadIdx.x;
    int w = tid >> 6, lane = tid & 63;
    int rowbase = blockIdx.x * 128;
    #pragma unroll
    for (int i = 0; i < 8; i++) bs[tid + i * 512] = Bfr[tid + i * 512];
    int row = rowbase + w * 16 + (lane & 15);
    int rowc = min(row, nrows - 1);
    const float4* X4 = (const float4*)X;
    bfrag a[4];
    #pragma unroll
    for (int kk = 0; kk < 4; kk++) {
        float4 f0 = X4[(size_t)rowc * 32 + kk * 8 + (lane >> 4) * 2];
        float4 f1 = X4[(size_t)rowc * 32 + kk * 8 + (lane >> 4) * 2 + 1];
        uint4 av = make_uint4(bf16rne(f0.x) | (bf16rne(f0.y) << 16),
                              bf16rne(f0.z) | (bf16rne(f0.w) << 16),
                              bf16rne(f1.x) | (bf16rne(f1.y) << 16),
                              bf16rne(f1.z) | (bf16rne(f1.w) << 16));
        a[kk] = *(const bfrag*)&av;
    }
    gemm_body(Y, dinv, nrows, rowbase, a, bs);
}

// out[node](bf16) = relu(bn(dinv[dst]*(sum Y'[src] + Y'[dst]) + bias));
// Y' pre-scaled by dinv[src]. 16 lanes/node, uint4/lane, padded CSR: no tail.
__global__ __launch_bounds__(256) void k_aggregate(const uint4* __restrict__ H4, const int* __restrict__ rowptr,
                                                   const int* __restrict__ rowend,
                                                   const int* __restrict__ csr_src,
                                                   const float* __restrict__ dinv,
                                                   const float* __restrict__ bias, const float* __restrict__ gamma,
                                                   const float* __restrict__ beta,
                                                   uint4* __restrict__ out4, int nnodes) {
    int tid = blockIdx.x * 256 + threadIdx.x;
    int node = tid >> 4;
    int l = tid & 15;                    // cols 8l .. 8l+7
    if (node >= nnodes) return;
    float acc[8];
    {
        uint4 hv = H4[(size_t)node * 16 + l];   // Y'[dst] (self term, pre-scaled)
        acc[0] = bflo(hv.x); acc[1] = bfhi(hv.x);
        acc[2] = bflo(hv.y); acc[3] = bfhi(hv.y);
        acc[4] = bflo(hv.z); acc[5] = bfhi(hv.z);
        acc[6] = bflo(hv.w); acc[7] = bfhi(hv.w);
    }
    int s = rowptr[node], e = rowend[node];
    for (int j = s; j < e; j += 8) {
        uint4 vv[8];
        #pragma unroll
        for (int q = 0; q < 8; q++) {
            int sv = csr_src[j + q];
            vv[q] = H4[(size_t)sv * 16 + l];
        }
        #pragma unroll
        for (int q = 0; q < 8; q++) {
            acc[0] += bflo(vv[q].x); acc[1] += bfhi(vv[q].x);
            acc[2] += bflo(vv[q].y); acc[3] += bfhi(vv[q].y);
            acc[4] += bflo(vv[q].z); acc[5] += bfhi(vv[q].z);
            acc[6] += bflo(vv[q].w); acc[7] += bfhi(vv[q].w);
        }
    }
    float dn = dinv[node];
    float4 bi0 = ((const float4*)bias)[l * 2],  bi1 = ((const float4*)bias)[l * 2 + 1];
    float4 ga0 = ((const float4*)gamma)[l * 2], ga1 = ((const float4*)gamma)[l * 2 + 1];
    float4 be0 = ((const float4*)beta)[l * 2],  be1 = ((const float4*)beta)[l * 2 + 1];
    float g[8] = {ga0.x, ga0.y, ga0.z, ga0.w, ga1.x, ga1.y, ga1.z, ga1.w};
    float bb[8] = {bi0.x, bi0.y, bi0.z, bi0.w, bi1.x, bi1.y, bi1.z, bi1.w};
    float bt[8] = {be0.x, be0.y, be0.z, be0.w, be1.x, be1.y, be1.z, be1.w};
    float r[8];
    #pragma unroll
    for (int i = 0; i < 8; i++) {
        float t = g[i] * INV1P;
        r[i] = fmaxf(fmaf(t * dn, acc[i], fmaf(t, bb[i], bt[i])), 0.f);
    }
    uint4 o;
    o.x = bf16rne(r[0]) | (bf16rne(r[1]) << 16);
    o.y = bf16rne(r[2]) | (bf16rne(r[3]) << 16);
    o.z = bf16rne(r[4]) | (bf16rne(r[5]) << 16);
    o.w = bf16rne(r[6]) | (bf16rne(r[7]) << 16);
    out4[(size_t)node * 16 + l] = o;
}

// pooled sums from bf16 H: 64 consecutive nodes per 64-thread block; batch sorted.
__global__ __launch_bounds__(64) void k_pool(const unsigned* __restrict__ Hf, const int* __restrict__ batch,
                                             float* __restrict__ pooled, float* __restrict__ cnt, int nnodes) {
    int t = threadIdx.x;
    int base = blockIdx.x * 64;
    if (base >= nnodes) return;
    int end = min(base + 64, nnodes);
    float ax = 0.f, ay = 0.f; int run = 0;
    int cur = batch[base];
    for (int i = base; i < end; i++) {
        int bg = batch[i];
        if (bg != cur) {
            atomicAdd(&pooled[(size_t)cur * 128 + 2 * t], ax);
            atomicAdd(&pooled[(size_t)cur * 128 + 2 * t + 1], ay);
            if (t == 0) atomicAdd(&cnt[cur], (float)run);
            ax = 0.f; ay = 0.f; run = 0; cur = bg;
        }
        unsigned u = Hf[(size_t)i * 64 + t];
        ax += bflo(u);
        ay += bfhi(u);
        run++;
    }
    atomicAdd(&pooled[(size_t)cur * 128 + 2 * t], ax);
    atomicAdd(&pooled[(size_t)cur * 128 + 2 * t + 1], ay);
    if (t == 0) atomicAdd(&cnt[cur], (float)run);
}

// classifier: one 64-thread block per graph. 128 -> 64 (relu) -> 10
__global__ __launch_bounds__(64) void k_classifier(const float* __restrict__ pooled, const float* __restrict__ cnt,
                                                   const float* __restrict__ Wc1, const float* __restrict__ bc1,
                                                   const float* __restrict__ Wc2, const float* __restrict__ bc2,
                                                   float* __restrict__ outp, int ngraphs) {
    __shared__ float p[128];
    __shared__ float z[64];
    int g = blockIdx.x;
    int tid = threadIdx.x;
    float inv = 1.0f / fmaxf(cnt[g], 1.0f);
    p[tid]      = pooled[(size_t)g * 128 + tid] * inv;
    p[tid + 64] = pooled[(size_t)g * 128 + 64 + tid] * inv;
    __syncthreads();
    float a = bc1[tid];
    #pragma unroll 8
    for (int k = 0; k < 128; k++) a += p[k] * Wc1[k * 64 + tid];
    z[tid] = fmaxf(a, 0.f);
    __syncthreads();
    if (tid < 10) {
        float o = bc2[tid];
        #pragma unroll 8
        for (int j = 0; j < 64; j++) o += z[j] * Wc2[j * 10 + tid];
        outp[(size_t)g * 10 + tid] = o;
    }
}

// ---------------- launch ----------------

static inline size_t align16(size_t v) { return (v + 15) & ~(size_t)15; }

extern "C" void kernel_launch(void* const* d_in, const int* in_sizes, int n_in,
                              void* d_out, int out_size, void* d_ws, size_t ws_size,
                              hipStream_t stream) {
    const float* x      = (const float*)d_in[0];
    const int*   ei     = (const int*)d_in[1];
    const int*   batch  = (const int*)d_in[2];
    const float* W1 = (const float*)d_in[3];  const float* b1 = (const float*)d_in[4];
    const float* W2 = (const float*)d_in[5];  const float* b2 = (const float*)d_in[6];
    const float* W3 = (const float*)d_in[7];  const float* b3 = (const float*)d_in[8];
    const float* g1 = (const float*)d_in[9];  const float* be1 = (const float*)d_in[10];
    const float* g2 = (const float*)d_in[11]; const float* be2 = (const float*)d_in[12];
    const float* g3 = (const float*)d_in[13]; const float* be3 = (const float*)d_in[14];
    const float* Wc1 = (const float*)d_in[15]; const float* bc1 = (const float*)d_in[16];
    const float* Wc2 = (const float*)d_in[17]; const float* bc2 = (const float*)d_in[18];

    const int N = in_sizes[0] / 128;
    const int E = in_sizes[1] / 2;
    const int G = out_size / 10;
    const int* srcp = ei;
    const int* dstp = ei + E;
    const int NB = (N + 511) >> 9;   // dst buckets of 512 nodes

    // workspace layout (16B-aligned slots)
    char* ws = (char*)d_ws;
    size_t off = 0;
    unsigned* bufA = (unsigned*)(ws + off); off = align16(off + (size_t)(N + 1) * 64 * 4);  // +1 zero row
    unsigned* bufB = (unsigned*)(ws + off); off = align16(off + (size_t)N * 64 * 4);
    uint4* Bfr1 = (uint4*)(ws + off); off = align16(off + 4096 * 16);
    uint4* Bfr2 = (uint4*)(ws + off); off = align16(off + 4096 * 16);
    uint4* Bfr3 = (uint4*)(ws + off); off = align16(off + 4096 * 16);
    int*   csr_src = (int*)(ws + off);  off = align16(off + (size_t)NB * CSRCAP * 4);
    unsigned* binned = (unsigned*)(ws + off); off = align16(off + (size_t)NB * BCAP * 4);
    float* dinv   = (float*)(ws + off); off = align16(off + (size_t)N * 4);
    int*   rowptr = (int*)(ws + off);   off = align16(off + (size_t)N * 4);
    int*   rowend = (int*)(ws + off);   off = align16(off + (size_t)N * 4);
    int*   gcursor = (int*)(ws + off);  off = align16(off + 256 * 4);
    float* pooled = (float*)(ws + off); off = align16(off + (size_t)G * 128 * 4);
    float* cnt    = (float*)(ws + off); off = align16(off + (size_t)G * 4);
    (void)ws_size;

    int gE8 = (E + 8191) / 8192;

    // zero the dummy gather row (row N of bufA); GEMMs never write it
    hipMemsetAsync(bufA + (size_t)N * 64, 0, 256, stream);

    // weight prep (independent of graph structure)
    k_prepw<<<8, 256, 0, stream>>>(W1, Bfr1);
    k_prepw<<<8, 256, 0, stream>>>(W2, Bfr2);
    k_prepw<<<8, 256, 0, stream>>>(W3, Bfr3);

    // graph structure: atomic-free CSR build (over-allocated buckets, padded rows)
    k_initcur2<<<1, 256, 0, stream>>>(gcursor);
    k_binA<<<gE8, 256, 0, stream>>>(srcp, dstp, gcursor, binned, E);
    k_binB2<<<NB, 256, 0, stream>>>(binned, gcursor, rowptr, rowend, dinv, csr_src, N, N);

    int gGemm = (N + 127) / 128;
    int gAgg  = (N * 16 + 255) / 256;

    // layer 1 (fp32 input, in-register convert)
    k_gemm_mfma_f32<<<gGemm, 512, 0, stream>>>(x, Bfr1, bufA, dinv, N);
    k_aggregate<<<gAgg, 256, 0, stream>>>((const uint4*)bufA, rowptr, rowend, csr_src, dinv, b1, g1, be1, (uint4*)bufB, N);
    // layer 2
    k_gemm_mfma<<<gGemm, 512, 0, stream>>>(bufB, Bfr2, bufA, dinv, N);
    k_aggregate<<<gAgg, 256, 0, stream>>>((const uint4*)bufA, rowptr, rowend, csr_src, dinv, b2, g2, be2, (uint4*)bufB, N);
    // layer 3
    k_gemm_mfma<<<gGemm, 512, 0, stream>>>(bufB, Bfr3, bufA, dinv, N);
    k_aggregate<<<gAgg, 256, 0, stream>>>((const uint4*)bufA, rowptr, rowend, csr_src, dinv, b3, g3, be3, (uint4*)bufB, N);

    // pooling
    hipMemsetAsync(pooled, 0, ((size_t)G * 128 + G) * 4, stream);
    int gPool = (N + 63) / 64;
    k_pool<<<gPool, 64, 0, stream>>>(bufB, batch, pooled, cnt, N);

    // classifier
    k_classifier<<<G, 64, 0, stream>>>(pooled, cnt, Wc1, bc1, Wc2, bc2, (float*)d_out, G);
}